// Round 1
// 658.260 us; speedup vs baseline: 1.0391x; 1.0391x over previous
//
#include <hip/hip_runtime.h>
#include <math.h>

#define N_NODES 20000
#define E_EDGES 320000
#define NHEADS 4
#define RMIN 2.2e-10f
#define THETA_MAX 1000.0f
#define SLOPE 0.2f

__device__ __forceinline__ float softplus_f(float x) {
    // log(1+exp(x)), stable; matches jax.nn.softplus
    return fmaxf(x, 0.0f) + log1pf(expf(-fabsf(x)));
}

// ---------------- CSR build ----------------
__global__ __launch_bounds__(256) void count_kernel(const int* __restrict__ dst,
                                                    int* __restrict__ deg) {
    int e = blockIdx.x * 256 + threadIdx.x;
    if (e < E_EDGES) atomicAdd(&deg[dst[e]], 1);
}

__global__ __launch_bounds__(256) void scan_kernel(const int* __restrict__ deg,
                                                   int* __restrict__ rowptr,
                                                   int* __restrict__ cursor) {
    __shared__ int part[256];
    int t = threadIdx.x;
    const int CH = (N_NODES + 255) / 256;  // 79
    int base = t * CH;
    int sum = 0;
    for (int i = 0; i < CH; ++i) {
        int idx = base + i;
        if (idx < N_NODES) sum += deg[idx];
    }
    part[t] = sum;
    __syncthreads();
    // Hillis-Steele inclusive scan
    for (int off = 1; off < 256; off <<= 1) {
        int v = (t >= off) ? part[t - off] : 0;
        __syncthreads();
        part[t] += v;
        __syncthreads();
    }
    int run = (t == 0) ? 0 : part[t - 1];
    for (int i = 0; i < CH; ++i) {
        int idx = base + i;
        if (idx < N_NODES) {
            rowptr[idx] = run;
            cursor[idx] = run;
            run += deg[idx];
        }
    }
    if (t == 255) rowptr[N_NODES] = run;
}

// also records dst node per CSR slot so edge weights can be computed CSR-ordered
__global__ __launch_bounds__(256) void scatter_kernel(const int* __restrict__ src,
                                                      const int* __restrict__ dst,
                                                      int* __restrict__ cursor,
                                                      int* __restrict__ csr,
                                                      int* __restrict__ dnd) {
    int e = blockIdx.x * 256 + threadIdx.x;
    if (e < E_EDGES) {
        int dn = dst[e];
        int p = atomicAdd(&cursor[dn], 1);
        csr[p] = src[e];
        dnd[p] = dn;
    }
}

// ---------------- per-edge (and self-loop) attention weights ----------------
// p < E: w4[p][h] = exp(leaky(s[csr[p]][h] + d[dnd[p]][h]))   (CSR-ordered, coalesced)
// p >= E: wself[n][h] = exp(leaky(s[n][h] + d[n][h]))  for n = p - E
__global__ __launch_bounds__(256) void eweight_kernel(const int* __restrict__ csr,
                                                      const int* __restrict__ dnd,
                                                      const float* __restrict__ s,
                                                      const float* __restrict__ d,
                                                      float* __restrict__ w4,
                                                      float* __restrict__ wself) {
    int p = blockIdx.x * 256 + threadIdx.x;
    if (p >= E_EDGES + N_NODES) return;
    int sn, dn;
    float* outp;
    if (p < E_EDGES) {
        sn = csr[p];
        dn = dnd[p];
        outp = w4 + 4 * (size_t)p;
    } else {
        sn = p - E_EDGES;
        dn = sn;
        outp = wself + 4 * (size_t)sn;
    }
    float4 sv = *(const float4*)(s + 4 * (size_t)sn);
    float4 dv = *(const float4*)(d + 4 * (size_t)dn);
    float4 wv;
    float e;
    e = sv.x + dv.x; e = e > 0.f ? e : SLOPE * e; wv.x = expf(e);
    e = sv.y + dv.y; e = e > 0.f ? e : SLOPE * e; wv.y = expf(e);
    e = sv.z + dv.z; e = e > 0.f ? e : SLOPE * e; wv.z = expf(e);
    e = sv.w + dv.w; e = e > 0.f ? e : SLOPE * e; wv.w = expf(e);
    *(float4*)outp = wv;
}

// ---------------- GEMM: out[M,NO] = A[M,K] * W[NO,K]^T, 64x64 tile ----------------
// MODE: 0 raw, 1 softplus(v+b), 2 clip(softplus(v+b),0.1,1000), 3 max(softplus(v+b),RMIN)
// TRANS: write out[col*M + row] (i.e. [NO, M] layout)
template <int MODE, bool TRANS>
__global__ __launch_bounds__(256) void gemm_kernel(const float* __restrict__ A,
                                                   const float* __restrict__ W,
                                                   const float* __restrict__ bias,
                                                   float* __restrict__ out,
                                                   int M, int K, int NO) {
    __shared__ float As[16][68];
    __shared__ float Bs[16][68];
    int tid = threadIdx.x;
    int tx = tid & 15, ty = tid >> 4;
    int bm = blockIdx.x * 64;
    int bn = blockIdx.y * 64;
    float acc[4][4] = {};
    for (int k0 = 0; k0 < K; k0 += 16) {
        {
            int m = tid >> 2;
            int kk0 = (tid & 3) * 4;
            int row = bm + m;
            float4 v = make_float4(0.f, 0.f, 0.f, 0.f);
            if (row < M) v = *(const float4*)(A + (size_t)row * K + k0 + kk0);
            As[kk0 + 0][m] = v.x; As[kk0 + 1][m] = v.y;
            As[kk0 + 2][m] = v.z; As[kk0 + 3][m] = v.w;
        }
        {
            int o = tid >> 2;
            int kk0 = (tid & 3) * 4;
            float4 v = *(const float4*)(W + (size_t)(bn + o) * K + k0 + kk0);
            Bs[kk0 + 0][o] = v.x; Bs[kk0 + 1][o] = v.y;
            Bs[kk0 + 2][o] = v.z; Bs[kk0 + 3][o] = v.w;
        }
        __syncthreads();
#pragma unroll
        for (int kk = 0; kk < 16; ++kk) {
            float a[4], b[4];
            *(float4*)a = *(const float4*)(&As[kk][ty * 4]);
            *(float4*)b = *(const float4*)(&Bs[kk][tx * 4]);
#pragma unroll
            for (int i = 0; i < 4; ++i)
#pragma unroll
                for (int j = 0; j < 4; ++j) acc[i][j] += a[i] * b[j];
        }
        __syncthreads();
    }
    int r0 = bm + ty * 4;
    int c0 = bn + tx * 4;
    float bv[4] = {0.f, 0.f, 0.f, 0.f};
    if (MODE != 0) *(float4*)bv = *(const float4*)(bias + c0);
    float vals[4][4];
#pragma unroll
    for (int i = 0; i < 4; ++i)
#pragma unroll
        for (int j = 0; j < 4; ++j) {
            float v = acc[i][j];
            if (MODE == 1) v = softplus_f(v + bv[j]);
            else if (MODE == 2) { v = softplus_f(v + bv[j]); v = fminf(fmaxf(v, 0.1f), 1000.0f); }
            else if (MODE == 3) { v = fmaxf(softplus_f(v + bv[j]), RMIN); }
            vals[i][j] = v;
        }
    if (!TRANS) {
#pragma unroll
        for (int i = 0; i < 4; ++i) {
            int row = r0 + i;
            if (row < M) *(float4*)(out + (size_t)row * NO + c0) = *(float4*)vals[i];
        }
    } else {
        if (r0 + 3 < M) {
#pragma unroll
            for (int j = 0; j < 4; ++j) {
                float col[4] = {vals[0][j], vals[1][j], vals[2][j], vals[3][j]};
                *(float4*)(out + (size_t)(c0 + j) * M + r0) = *(float4*)col;
            }
        } else {
#pragma unroll
            for (int i = 0; i < 4; ++i) {
                int row = r0 + i;
                if (row < M)
#pragma unroll
                    for (int j = 0; j < 4; ++j) out[(size_t)(c0 + j) * M + row] = vals[i][j];
            }
        }
    }
}

// ---------------- per-node attention logits s,d ----------------
template <int F, int CPER>
__global__ __launch_bounds__(256) void sd_kernel(const float* __restrict__ xw,
                                                 const float* __restrict__ asrc,
                                                 const float* __restrict__ adst,
                                                 float* __restrict__ s,
                                                 float* __restrict__ d) {
    int wave = threadIdx.x >> 6;
    int lane = threadIdx.x & 63;
    int n = blockIdx.x * 4 + wave;
    if (n >= N_NODES) return;
    float ss[NHEADS] = {0, 0, 0, 0}, dd[NHEADS] = {0, 0, 0, 0};
#pragma unroll
    for (int j = 0; j < F / 64; ++j) {
        int c = j * 64 + lane;
        int h = c / CPER;
        int cc = c % CPER;
        float v = xw[(size_t)n * F + c];
        ss[h] += v * asrc[h * CPER + cc];
        dd[h] += v * adst[h * CPER + cc];
    }
#pragma unroll
    for (int off = 32; off > 0; off >>= 1) {
#pragma unroll
        for (int h = 0; h < NHEADS; ++h) {
            ss[h] += __shfl_xor(ss[h], off, 64);
            dd[h] += __shfl_xor(dd[h], off, 64);
        }
    }
    if (lane == 0) {
#pragma unroll
        for (int h = 0; h < NHEADS; ++h) {
            s[n * NHEADS + h] = ss[h];
            d[n * NHEADS + h] = dd[h];
        }
    }
}

// per-head weight select: compile-time for CPER=64 (h==j), cndmask on lane bit 5 for CPER=32
template <int CPER>
__device__ __forceinline__ float pick_w(float4 w, int j, int lane) {
    if constexpr (CPER == 64) {
        return j == 0 ? w.x : (j == 1 ? w.y : (j == 2 ? w.z : w.w));
    } else {
        float lo = (j == 0) ? w.x : w.z;
        float hi = (j == 0) ? w.y : w.w;
        return (lane & 32) ? hi : lo;
    }
}

// ---------------- GAT aggregation: one wave per node, precomputed weights ----------------
template <int F, int CPER>
__global__ __launch_bounds__(256) void agg_kernel(const float* __restrict__ xw,
                                                  const int* __restrict__ rowptr,
                                                  const int* __restrict__ csr,
                                                  const float* __restrict__ w4,
                                                  const float* __restrict__ wself,
                                                  const float* __restrict__ bias,
                                                  float* __restrict__ out) {
    int wave = threadIdx.x >> 6;
    int lane = threadIdx.x & 63;
    int n = blockIdx.x * 4 + wave;
    if (n >= N_NODES) return;
    constexpr int J = F / 64;

    float4 wl = *(const float4*)(wself + 4 * (size_t)n);
    float den[NHEADS] = {wl.x, wl.y, wl.z, wl.w};
    float acc[J];
#pragma unroll
    for (int j = 0; j < J; ++j) {
        int c = j * 64 + lane;
        acc[j] = pick_w<CPER>(wl, j, lane) * xw[(size_t)n * F + c];
    }

    int beg = rowptr[n], end = rowptr[n + 1];
    int idx = beg;
    // 2x unrolled over edges: overlap the two row gathers
    for (; idx + 2 <= end; idx += 2) {
        int sa = csr[idx], sb = csr[idx + 1];
        float4 wa = *(const float4*)(w4 + 4 * (size_t)idx);
        float4 wb = *(const float4*)(w4 + 4 * (size_t)(idx + 1));
        den[0] += wa.x + wb.x;
        den[1] += wa.y + wb.y;
        den[2] += wa.z + wb.z;
        den[3] += wa.w + wb.w;
        const float* ra = xw + (size_t)sa * F;
        const float* rb = xw + (size_t)sb * F;
#pragma unroll
        for (int j = 0; j < J; ++j) {
            int c = j * 64 + lane;
            acc[j] += pick_w<CPER>(wa, j, lane) * ra[c];
            acc[j] += pick_w<CPER>(wb, j, lane) * rb[c];
        }
    }
    if (idx < end) {
        int sa = csr[idx];
        float4 wa = *(const float4*)(w4 + 4 * (size_t)idx);
        den[0] += wa.x;
        den[1] += wa.y;
        den[2] += wa.z;
        den[3] += wa.w;
        const float* ra = xw + (size_t)sa * F;
#pragma unroll
        for (int j = 0; j < J; ++j) {
            int c = j * 64 + lane;
            acc[j] += pick_w<CPER>(wa, j, lane) * ra[c];
        }
    }

#pragma unroll
    for (int j = 0; j < J; ++j) {
        int c = j * 64 + lane;
        float dv;
        if constexpr (CPER == 64) dv = den[j];
        else dv = (lane & 32) ? den[2 * j + 1] : den[2 * j];
        out[(size_t)n * F + c] = acc[j] / (dv + 1e-16f) + bias[c];
    }
}

// ---------------- Weibull reparameterization ----------------
__global__ __launch_bounds__(256) void theta_kernel(const float* __restrict__ eps,
                                                    const float* __restrict__ kptr,
                                                    float* __restrict__ lptr,
                                                    float* __restrict__ theta, int ZN) {
    int i = blockIdx.x * 256 + threadIdx.x;
    if (i >= ZN) return;
    float k = kptr[i];
    float invk = 1.0f / k;
    float lg = expf(lgammaf(1.0f + invk));
    float l = lptr[i] / lg;
    lptr[i] = l;
    float acc = 0.0f;
#pragma unroll
    for (int ss = 0; ss < 10; ++ss) {
        float u = eps[(size_t)ss * ZN + i];
        float v = -logf(fmaxf(1.0f - u, RMIN));
        // v^invk = exp2(log2(v)*invk); v==0 -> log2=-inf -> 0, matches power semantics
        acc += exp2f(log2f(v) * invk);
    }
    float th = l * acc * 0.1f;
    th = fminf(fmaxf(th, RMIN), THETA_MAX);
    theta[i] = th;
}

extern "C" void kernel_launch(void* const* d_in, const int* in_sizes, int n_in,
                              void* d_out, int out_size, void* d_ws, size_t ws_size,
                              hipStream_t stream) {
    const float* x     = (const float*)d_in[0];
    const int*   eidx  = (const int*)d_in[1];
    const float* gatW0 = (const float*)d_in[2];
    const float* asrc0 = (const float*)d_in[3];
    const float* adst0 = (const float*)d_in[4];
    const float* gatb0 = (const float*)d_in[5];
    const float* fcW0  = (const float*)d_in[6];
    const float* fcb0  = (const float*)d_in[7];
    const float* shW0  = (const float*)d_in[8];
    const float* shb0  = (const float*)d_in[9];
    const float* scW0  = (const float*)d_in[10];
    const float* scb0  = (const float*)d_in[11];
    const float* gatW1 = (const float*)d_in[12];
    const float* asrc1 = (const float*)d_in[13];
    const float* adst1 = (const float*)d_in[14];
    const float* gatb1 = (const float*)d_in[15];
    const float* fcW1  = (const float*)d_in[16];
    const float* fcb1  = (const float*)d_in[17];
    const float* shW1  = (const float*)d_in[18];
    const float* shb1  = (const float*)d_in[19];
    const float* scW1  = (const float*)d_in[20];
    const float* scb1  = (const float*)d_in[21];
    const float* eps0  = (const float*)d_in[22];
    const float* eps1  = (const float*)d_in[23];

    const int* e_src = eidx;
    const int* e_dst = eidx + E_EDGES;

    // workspace carve-up
    size_t off = 0;
    auto carve = [&](size_t elems) {
        void* p = (char*)d_ws + off;
        off += ((elems * 4 + 255) / 256) * 256;
        return p;
    };
    float* xw0 = (float*)carve(20000u * 256);
    float* h0  = (float*)carve(20000u * 256);
    float* z0  = (float*)carve(20000u * 128);
    float* xw1 = (float*)carve(20000u * 128);
    float* h1  = (float*)carve(20000u * 128);
    float* z1  = (float*)carve(20000u * 64);
    float* s0  = (float*)carve(20000u * 4);
    float* d0  = (float*)carve(20000u * 4);
    float* s1  = (float*)carve(20000u * 4);
    float* d1  = (float*)carve(20000u * 4);
    int* deg    = (int*)carve(20000);
    int* rowptr = (int*)carve(20001);
    int* cursor = (int*)carve(20000);
    int* csr    = (int*)carve(E_EDGES);
    int* dnd    = (int*)carve(E_EDGES);
    float* w4    = (float*)carve((size_t)E_EDGES * 4);  // reused across both layers
    float* wself = (float*)carve(20000u * 4);

    float* out    = (float*)d_out;
    float* theta0 = out;
    float* theta1 = out + 2560000;
    float* k0     = out + 3840000;
    float* k1     = out + 6400000;
    float* l0     = out + 7680000;
    float* l1     = out + 10240000;

    const int M = N_NODES;
    dim3 blk(256);
    const int EW_BLOCKS = (E_EDGES + N_NODES + 255) / 256;

    // CSR build
    (void)hipMemsetAsync(deg, 0, N_NODES * sizeof(int), stream);
    count_kernel<<<(E_EDGES + 255) / 256, blk, 0, stream>>>(e_dst, deg);
    scan_kernel<<<1, blk, 0, stream>>>(deg, rowptr, cursor);
    scatter_kernel<<<(E_EDGES + 255) / 256, blk, 0, stream>>>(e_src, e_dst, cursor, csr, dnd);

    // layer 0
    gemm_kernel<0, false><<<dim3(313, 4), blk, 0, stream>>>(x, gatW0, nullptr, xw0, M, 256, 256);
    sd_kernel<256, 64><<<5000, blk, 0, stream>>>(xw0, asrc0, adst0, s0, d0);
    eweight_kernel<<<EW_BLOCKS, blk, 0, stream>>>(csr, dnd, s0, d0, w4, wself);
    agg_kernel<256, 64><<<5000, blk, 0, stream>>>(xw0, rowptr, csr, w4, wself, gatb0, h0);
    gemm_kernel<1, false><<<dim3(313, 2), blk, 0, stream>>>(h0, fcW0, fcb0, z0, M, 256, 128);

    // layer 1
    gemm_kernel<0, false><<<dim3(313, 2), blk, 0, stream>>>(h0, gatW1, nullptr, xw1, M, 256, 128);
    sd_kernel<128, 32><<<5000, blk, 0, stream>>>(xw1, asrc1, adst1, s1, d1);
    eweight_kernel<<<EW_BLOCKS, blk, 0, stream>>>(csr, dnd, s1, d1, w4, wself);
    agg_kernel<128, 32><<<5000, blk, 0, stream>>>(xw1, rowptr, csr, w4, wself, gatb1, h1);
    gemm_kernel<1, false><<<dim3(313, 1), blk, 0, stream>>>(h1, fcW1, fcb1, z1, M, 128, 64);

    // heads: k and raw l (transposed [z, N] into d_out)
    gemm_kernel<2, true><<<dim3(313, 2), blk, 0, stream>>>(z0, shW0, shb0, k0, M, 128, 128);
    gemm_kernel<3, true><<<dim3(313, 2), blk, 0, stream>>>(z0, scW0, scb0, l0, M, 128, 128);
    gemm_kernel<2, true><<<dim3(313, 1), blk, 0, stream>>>(z1, shW1, shb1, k1, M, 64, 64);
    gemm_kernel<3, true><<<dim3(313, 1), blk, 0, stream>>>(z1, scW1, scb1, l1, M, 64, 64);

    // reparameterize (finalizes l in-place, writes theta)
    theta_kernel<<<(2560000 + 255) / 256, blk, 0, stream>>>(eps0, k0, l0, theta0, 2560000);
    theta_kernel<<<(1280000 + 255) / 256, blk, 0, stream>>>(eps1, k1, l1, theta1, 1280000);
}

// Round 2
// 647.757 us; speedup vs baseline: 1.0560x; 1.0162x over previous
//
#include <hip/hip_runtime.h>
#include <math.h>

#define N_NODES 20000
#define E_EDGES 320000
#define NHEADS 4
#define RMIN 2.2e-10f
#define THETA_MAX 1000.0f
#define SLOPE 0.2f

__device__ __forceinline__ float softplus_f(float x) {
    // log(1+exp(x)), stable; matches jax.nn.softplus
    return fmaxf(x, 0.0f) + log1pf(expf(-fabsf(x)));
}

// ---------------- CSR build ----------------
__global__ __launch_bounds__(256) void count_kernel(const int* __restrict__ dst,
                                                    int* __restrict__ deg) {
    int e = blockIdx.x * 256 + threadIdx.x;
    if (e < E_EDGES) atomicAdd(&deg[dst[e]], 1);
}

__global__ __launch_bounds__(256) void scan_kernel(const int* __restrict__ deg,
                                                   int* __restrict__ rowptr,
                                                   int* __restrict__ cursor) {
    __shared__ int part[256];
    int t = threadIdx.x;
    const int CH = (N_NODES + 255) / 256;  // 79
    int base = t * CH;
    int sum = 0;
    for (int i = 0; i < CH; ++i) {
        int idx = base + i;
        if (idx < N_NODES) sum += deg[idx];
    }
    part[t] = sum;
    __syncthreads();
    // Hillis-Steele inclusive scan
    for (int off = 1; off < 256; off <<= 1) {
        int v = (t >= off) ? part[t - off] : 0;
        __syncthreads();
        part[t] += v;
        __syncthreads();
    }
    int run = (t == 0) ? 0 : part[t - 1];
    for (int i = 0; i < CH; ++i) {
        int idx = base + i;
        if (idx < N_NODES) {
            rowptr[idx] = run;
            cursor[idx] = run;
            run += deg[idx];
        }
    }
    if (t == 255) rowptr[N_NODES] = run;
}

// also records dst node per CSR slot so edge weights can be computed CSR-ordered
__global__ __launch_bounds__(256) void scatter_kernel(const int* __restrict__ src,
                                                      const int* __restrict__ dst,
                                                      int* __restrict__ cursor,
                                                      int* __restrict__ csr,
                                                      int* __restrict__ dnd) {
    int e = blockIdx.x * 256 + threadIdx.x;
    if (e < E_EDGES) {
        int dn = dst[e];
        int p = atomicAdd(&cursor[dn], 1);
        csr[p] = src[e];
        dnd[p] = dn;
    }
}

// ---------------- per-edge (and self-loop) attention weights ----------------
__global__ __launch_bounds__(256) void eweight_kernel(const int* __restrict__ csr,
                                                      const int* __restrict__ dnd,
                                                      const float* __restrict__ s,
                                                      const float* __restrict__ d,
                                                      float* __restrict__ w4,
                                                      float* __restrict__ wself) {
    int p = blockIdx.x * 256 + threadIdx.x;
    if (p >= E_EDGES + N_NODES) return;
    int sn, dn;
    float* outp;
    if (p < E_EDGES) {
        sn = csr[p];
        dn = dnd[p];
        outp = w4 + 4 * (size_t)p;
    } else {
        sn = p - E_EDGES;
        dn = sn;
        outp = wself + 4 * (size_t)sn;
    }
    float4 sv = *(const float4*)(s + 4 * (size_t)sn);
    float4 dv = *(const float4*)(d + 4 * (size_t)dn);
    float4 wv;
    float e;
    e = sv.x + dv.x; e = e > 0.f ? e : SLOPE * e; wv.x = expf(e);
    e = sv.y + dv.y; e = e > 0.f ? e : SLOPE * e; wv.y = expf(e);
    e = sv.z + dv.z; e = e > 0.f ? e : SLOPE * e; wv.z = expf(e);
    e = sv.w + dv.w; e = e > 0.f ? e : SLOPE * e; wv.w = expf(e);
    *(float4*)outp = wv;
}

// ---------------- GEMM: 128x64 tile, 8x4 micro-tile, dual-output merge ----------------
// out = A[M,K] * [W0;W1][NO,K]^T. Columns [0,split) -> out0 (MODE0), [split,NO) -> out1 (MODE1).
// MODE: 0 raw, 1 softplus(v+b), 2 clip(softplus(v+b),0.1,1000), 3 max(softplus(v+b),RMIN)
// TRANS: write out[col*M + row] ([NO, M] layout)
template <int MODE, bool TRANS>
__device__ __forceinline__ void gemm_epilogue(const float acc[8][4],
                                              const float* __restrict__ bp,
                                              float* __restrict__ op,
                                              int ow, int colbase, int r0, int lc, int M) {
    float bv[4] = {0.f, 0.f, 0.f, 0.f};
    if (MODE != 0) *(float4*)bv = *(const float4*)(bp + colbase + lc);
    float vals[8][4];
#pragma unroll
    for (int i = 0; i < 8; ++i)
#pragma unroll
        for (int j = 0; j < 4; ++j) {
            float v = acc[i][j];
            if (MODE == 1) v = softplus_f(v + bv[j]);
            else if (MODE == 2) { v = softplus_f(v + bv[j]); v = fminf(fmaxf(v, 0.1f), 1000.0f); }
            else if (MODE == 3) { v = fmaxf(softplus_f(v + bv[j]), RMIN); }
            vals[i][j] = v;
        }
    if (!TRANS) {
#pragma unroll
        for (int i = 0; i < 8; ++i) {
            int row = r0 + i;
            if (row < M) *(float4*)(op + (size_t)row * ow + colbase + lc) = *(float4*)vals[i];
        }
    } else {
        if (r0 + 7 < M) {
#pragma unroll
            for (int j = 0; j < 4; ++j) {
                int c = colbase + lc + j;
                float c0[4] = {vals[0][j], vals[1][j], vals[2][j], vals[3][j]};
                float c1[4] = {vals[4][j], vals[5][j], vals[6][j], vals[7][j]};
                *(float4*)(op + (size_t)c * M + r0) = *(float4*)c0;
                *(float4*)(op + (size_t)c * M + r0 + 4) = *(float4*)c1;
            }
        } else {
#pragma unroll
            for (int i = 0; i < 8; ++i) {
                int row = r0 + i;
                if (row < M)
#pragma unroll
                    for (int j = 0; j < 4; ++j) op[(size_t)(colbase + lc + j) * M + row] = vals[i][j];
            }
        }
    }
}

template <int MODE0, int MODE1, bool TRANS>
__global__ __launch_bounds__(256) void gemm128_kernel(const float* __restrict__ A,
                                                      const float* __restrict__ W0,
                                                      const float* __restrict__ W1,
                                                      const float* __restrict__ b0p,
                                                      const float* __restrict__ b1p,
                                                      float* __restrict__ out0,
                                                      float* __restrict__ out1,
                                                      int M, int K, int split, int no1) {
    __shared__ float As[16][132];
    __shared__ float Bs[16][68];
    int tid = threadIdx.x;
    int tx = tid & 15, ty = tid >> 4;       // tx: 16 col-groups of 4, ty: 16 row-groups of 8
    int bm = blockIdx.x * 128;
    int bn = blockIdx.y * 64;
    bool first = bn < split;
    const float* W = first ? (W0 + (size_t)bn * K) : (W1 + (size_t)(bn - split) * K);
    int mrow = tid >> 2;                    // 0..63
    int kk0 = (tid & 3) * 4;                // 0,4,8,12
    float acc[8][4] = {};
    for (int k0 = 0; k0 < K; k0 += 16) {
        // A-stage: 128 rows x 16 k, two rows per thread, 16B contiguous per lane
#pragma unroll
        for (int r = 0; r < 2; ++r) {
            int m = mrow + r * 64;
            int row = bm + m;
            float4 v = make_float4(0.f, 0.f, 0.f, 0.f);
            if (row < M) v = *(const float4*)(A + (size_t)row * K + k0 + kk0);
            As[kk0 + 0][m] = v.x; As[kk0 + 1][m] = v.y;
            As[kk0 + 2][m] = v.z; As[kk0 + 3][m] = v.w;
        }
        // B-stage: 64 rows x 16 k
        {
            float4 v = *(const float4*)(W + (size_t)mrow * K + k0 + kk0);
            Bs[kk0 + 0][mrow] = v.x; Bs[kk0 + 1][mrow] = v.y;
            Bs[kk0 + 2][mrow] = v.z; Bs[kk0 + 3][mrow] = v.w;
        }
        __syncthreads();
#pragma unroll
        for (int kk = 0; kk < 16; ++kk) {
            float a[8], b[4];
            *(float4*)&a[0] = *(const float4*)(&As[kk][ty * 8]);
            *(float4*)&a[4] = *(const float4*)(&As[kk][ty * 8 + 4]);
            *(float4*)&b[0] = *(const float4*)(&Bs[kk][tx * 4]);
#pragma unroll
            for (int i = 0; i < 8; ++i)
#pragma unroll
                for (int j = 0; j < 4; ++j) acc[i][j] += a[i] * b[j];
        }
        __syncthreads();
    }
    int r0 = bm + ty * 8;
    int lc = tx * 4;
    if (first) gemm_epilogue<MODE0, TRANS>(acc, b0p, out0, split, bn, r0, lc, M);
    else       gemm_epilogue<MODE1, TRANS>(acc, b1p, out1, no1, bn - split, r0, lc, M);
}

// ---------------- per-node attention logits s,d ----------------
template <int F, int CPER>
__global__ __launch_bounds__(256) void sd_kernel(const float* __restrict__ xw,
                                                 const float* __restrict__ asrc,
                                                 const float* __restrict__ adst,
                                                 float* __restrict__ s,
                                                 float* __restrict__ d) {
    int wave = threadIdx.x >> 6;
    int lane = threadIdx.x & 63;
    int n = blockIdx.x * 4 + wave;
    if (n >= N_NODES) return;
    float ss[NHEADS] = {0, 0, 0, 0}, dd[NHEADS] = {0, 0, 0, 0};
#pragma unroll
    for (int j = 0; j < F / 64; ++j) {
        int c = j * 64 + lane;
        int h = c / CPER;
        int cc = c % CPER;
        float v = xw[(size_t)n * F + c];
        ss[h] += v * asrc[h * CPER + cc];
        dd[h] += v * adst[h * CPER + cc];
    }
#pragma unroll
    for (int off = 32; off > 0; off >>= 1) {
#pragma unroll
        for (int h = 0; h < NHEADS; ++h) {
            ss[h] += __shfl_xor(ss[h], off, 64);
            dd[h] += __shfl_xor(dd[h], off, 64);
        }
    }
    if (lane == 0) {
#pragma unroll
        for (int h = 0; h < NHEADS; ++h) {
            s[n * NHEADS + h] = ss[h];
            d[n * NHEADS + h] = dd[h];
        }
    }
}

// per-head weight select: compile-time for CPER=64 (h==j), cndmask on lane bit 5 for CPER=32
template <int CPER>
__device__ __forceinline__ float pick_w(float4 w, int j, int lane) {
    if constexpr (CPER == 64) {
        return j == 0 ? w.x : (j == 1 ? w.y : (j == 2 ? w.z : w.w));
    } else {
        float lo = (j == 0) ? w.x : w.z;
        float hi = (j == 0) ? w.y : w.w;
        return (lane & 32) ? hi : lo;
    }
}

// ---------------- GAT aggregation: one wave per node, precomputed weights ----------------
template <int F, int CPER>
__global__ __launch_bounds__(256) void agg_kernel(const float* __restrict__ xw,
                                                  const int* __restrict__ rowptr,
                                                  const int* __restrict__ csr,
                                                  const float* __restrict__ w4,
                                                  const float* __restrict__ wself,
                                                  const float* __restrict__ bias,
                                                  float* __restrict__ out) {
    int wave = threadIdx.x >> 6;
    int lane = threadIdx.x & 63;
    int n = blockIdx.x * 4 + wave;
    if (n >= N_NODES) return;
    constexpr int J = F / 64;

    float4 wl = *(const float4*)(wself + 4 * (size_t)n);
    float den[NHEADS] = {wl.x, wl.y, wl.z, wl.w};
    float acc[J];
#pragma unroll
    for (int j = 0; j < J; ++j) {
        int c = j * 64 + lane;
        acc[j] = pick_w<CPER>(wl, j, lane) * xw[(size_t)n * F + c];
    }

    int beg = rowptr[n], end = rowptr[n + 1];
    int idx = beg;
    for (; idx + 2 <= end; idx += 2) {
        int sa = csr[idx], sb = csr[idx + 1];
        float4 wa = *(const float4*)(w4 + 4 * (size_t)idx);
        float4 wb = *(const float4*)(w4 + 4 * (size_t)(idx + 1));
        den[0] += wa.x + wb.x;
        den[1] += wa.y + wb.y;
        den[2] += wa.z + wb.z;
        den[3] += wa.w + wb.w;
        const float* ra = xw + (size_t)sa * F;
        const float* rb = xw + (size_t)sb * F;
#pragma unroll
        for (int j = 0; j < J; ++j) {
            int c = j * 64 + lane;
            acc[j] += pick_w<CPER>(wa, j, lane) * ra[c];
            acc[j] += pick_w<CPER>(wb, j, lane) * rb[c];
        }
    }
    if (idx < end) {
        int sa = csr[idx];
        float4 wa = *(const float4*)(w4 + 4 * (size_t)idx);
        den[0] += wa.x;
        den[1] += wa.y;
        den[2] += wa.z;
        den[3] += wa.w;
        const float* ra = xw + (size_t)sa * F;
#pragma unroll
        for (int j = 0; j < J; ++j) {
            int c = j * 64 + lane;
            acc[j] += pick_w<CPER>(wa, j, lane) * ra[c];
        }
    }

#pragma unroll
    for (int j = 0; j < J; ++j) {
        int c = j * 64 + lane;
        float dv;
        if constexpr (CPER == 64) dv = den[j];
        else dv = (lane & 32) ? den[2 * j + 1] : den[2 * j];
        out[(size_t)n * F + c] = acc[j] / (dv + 1e-16f) + bias[c];
    }
}

// ---------------- Weibull reparameterization ----------------
__global__ __launch_bounds__(256) void theta_kernel(const float* __restrict__ eps,
                                                    const float* __restrict__ kptr,
                                                    float* __restrict__ lptr,
                                                    float* __restrict__ theta, int ZN) {
    int i = blockIdx.x * 256 + threadIdx.x;
    if (i >= ZN) return;
    float k = kptr[i];
    float invk = 1.0f / k;
    float lg = expf(lgammaf(1.0f + invk));
    float l = lptr[i] / lg;
    lptr[i] = l;
    float acc = 0.0f;
#pragma unroll
    for (int ss = 0; ss < 10; ++ss) {
        float u = eps[(size_t)ss * ZN + i];
        float v = -logf(fmaxf(1.0f - u, RMIN));
        acc += exp2f(log2f(v) * invk);
    }
    float th = l * acc * 0.1f;
    th = fminf(fmaxf(th, RMIN), THETA_MAX);
    theta[i] = th;
}

extern "C" void kernel_launch(void* const* d_in, const int* in_sizes, int n_in,
                              void* d_out, int out_size, void* d_ws, size_t ws_size,
                              hipStream_t stream) {
    const float* x     = (const float*)d_in[0];
    const int*   eidx  = (const int*)d_in[1];
    const float* gatW0 = (const float*)d_in[2];
    const float* asrc0 = (const float*)d_in[3];
    const float* adst0 = (const float*)d_in[4];
    const float* gatb0 = (const float*)d_in[5];
    const float* fcW0  = (const float*)d_in[6];
    const float* fcb0  = (const float*)d_in[7];
    const float* shW0  = (const float*)d_in[8];
    const float* shb0  = (const float*)d_in[9];
    const float* scW0  = (const float*)d_in[10];
    const float* scb0  = (const float*)d_in[11];
    const float* gatW1 = (const float*)d_in[12];
    const float* asrc1 = (const float*)d_in[13];
    const float* adst1 = (const float*)d_in[14];
    const float* gatb1 = (const float*)d_in[15];
    const float* fcW1  = (const float*)d_in[16];
    const float* fcb1  = (const float*)d_in[17];
    const float* shW1  = (const float*)d_in[18];
    const float* shb1  = (const float*)d_in[19];
    const float* scW1  = (const float*)d_in[20];
    const float* scb1  = (const float*)d_in[21];
    const float* eps0  = (const float*)d_in[22];
    const float* eps1  = (const float*)d_in[23];

    const int* e_src = eidx;
    const int* e_dst = eidx + E_EDGES;

    // workspace carve-up
    size_t off = 0;
    auto carve = [&](size_t elems) {
        void* p = (char*)d_ws + off;
        off += ((elems * 4 + 255) / 256) * 256;
        return p;
    };
    float* xw0 = (float*)carve(20000u * 256);
    float* h0  = (float*)carve(20000u * 256);
    float* z0  = (float*)carve(20000u * 128);
    float* xw1 = (float*)carve(20000u * 128);
    float* h1  = (float*)carve(20000u * 128);
    float* z1  = (float*)carve(20000u * 64);
    float* s0  = (float*)carve(20000u * 4);
    float* d0  = (float*)carve(20000u * 4);
    float* s1  = (float*)carve(20000u * 4);
    float* d1  = (float*)carve(20000u * 4);
    int* deg    = (int*)carve(20000);
    int* rowptr = (int*)carve(20001);
    int* cursor = (int*)carve(20000);
    int* csr    = (int*)carve(E_EDGES);
    int* dnd    = (int*)carve(E_EDGES);
    float* w4    = (float*)carve((size_t)E_EDGES * 4);  // reused across both layers
    float* wself = (float*)carve(20000u * 4);

    float* out    = (float*)d_out;
    float* theta0 = out;
    float* theta1 = out + 2560000;
    float* k0     = out + 3840000;
    float* k1     = out + 6400000;
    float* l0     = out + 7680000;
    float* l1     = out + 10240000;

    const int M = N_NODES;
    dim3 blk(256);
    const int GX = (N_NODES + 127) / 128;  // 157
    const int EW_BLOCKS = (E_EDGES + N_NODES + 255) / 256;

    // CSR build
    (void)hipMemsetAsync(deg, 0, N_NODES * sizeof(int), stream);
    count_kernel<<<(E_EDGES + 255) / 256, blk, 0, stream>>>(e_dst, deg);
    scan_kernel<<<1, blk, 0, stream>>>(deg, rowptr, cursor);
    scatter_kernel<<<(E_EDGES + 255) / 256, blk, 0, stream>>>(e_src, e_dst, cursor, csr, dnd);

    // layer 0: xw0 = x @ gatW0^T
    gemm128_kernel<0, 0, false><<<dim3(GX, 4), blk, 0, stream>>>(
        x, gatW0, nullptr, nullptr, nullptr, xw0, nullptr, M, 256, 256, 0);
    sd_kernel<256, 64><<<5000, blk, 0, stream>>>(xw0, asrc0, adst0, s0, d0);
    eweight_kernel<<<EW_BLOCKS, blk, 0, stream>>>(csr, dnd, s0, d0, w4, wself);
    agg_kernel<256, 64><<<5000, blk, 0, stream>>>(xw0, rowptr, csr, w4, wself, gatb0, h0);

    // merged: z0 = softplus(h0 @ fcW0^T + b) | xw1 = h0 @ gatW1^T
    gemm128_kernel<1, 0, false><<<dim3(GX, 4), blk, 0, stream>>>(
        h0, fcW0, gatW1, fcb0, nullptr, z0, xw1, M, 256, 128, 128);

    // layer 1
    sd_kernel<128, 32><<<5000, blk, 0, stream>>>(xw1, asrc1, adst1, s1, d1);
    eweight_kernel<<<EW_BLOCKS, blk, 0, stream>>>(csr, dnd, s1, d1, w4, wself);
    agg_kernel<128, 32><<<5000, blk, 0, stream>>>(xw1, rowptr, csr, w4, wself, gatb1, h1);
    gemm128_kernel<1, 0, false><<<dim3(GX, 1), blk, 0, stream>>>(
        h1, fcW1, nullptr, fcb1, nullptr, z1, nullptr, M, 128, 64, 0);

    // merged heads (transposed [z, N] into d_out): k = clip(sp(.)), l = max(sp(.), RMIN)
    gemm128_kernel<2, 3, true><<<dim3(GX, 4), blk, 0, stream>>>(
        z0, shW0, scW0, shb0, scb0, k0, l0, M, 128, 128, 128);
    gemm128_kernel<2, 3, true><<<dim3(GX, 2), blk, 0, stream>>>(
        z1, shW1, scW1, shb1, scb1, k1, l1, M, 64, 64, 64);

    // reparameterize (finalizes l in-place, writes theta)
    theta_kernel<<<(2560000 + 255) / 256, blk, 0, stream>>>(eps0, k0, l0, theta0, 2560000);
    theta_kernel<<<(1280000 + 255) / 256, blk, 0, stream>>>(eps1, k1, l1, theta1, 1280000);
}

// Round 3
// 626.322 us; speedup vs baseline: 1.0921x; 1.0342x over previous
//
#include <hip/hip_runtime.h>
#include <math.h>

#define N_NODES 20000
#define E_EDGES 320000
#define NHEADS 4
#define RMIN 2.2e-10f
#define THETA_MAX 1000.0f
#define SLOPE 0.2f

__device__ __forceinline__ float softplus_f(float x) {
    // log(1+exp(x)), stable; matches jax.nn.softplus
    return fmaxf(x, 0.0f) + log1pf(expf(-fabsf(x)));
}

// ---------------- CSR build ----------------
__global__ __launch_bounds__(256) void count_kernel(const int* __restrict__ dst,
                                                    int* __restrict__ deg) {
    int e = blockIdx.x * 256 + threadIdx.x;
    if (e < E_EDGES) atomicAdd(&deg[dst[e]], 1);
}

__global__ __launch_bounds__(256) void scan_kernel(const int* __restrict__ deg,
                                                   int* __restrict__ rowptr,
                                                   int* __restrict__ cursor) {
    __shared__ int part[256];
    int t = threadIdx.x;
    const int CH = (N_NODES + 255) / 256;  // 79
    int base = t * CH;
    int sum = 0;
    for (int i = 0; i < CH; ++i) {
        int idx = base + i;
        if (idx < N_NODES) sum += deg[idx];
    }
    part[t] = sum;
    __syncthreads();
    // Hillis-Steele inclusive scan
    for (int off = 1; off < 256; off <<= 1) {
        int v = (t >= off) ? part[t - off] : 0;
        __syncthreads();
        part[t] += v;
        __syncthreads();
    }
    int run = (t == 0) ? 0 : part[t - 1];
    for (int i = 0; i < CH; ++i) {
        int idx = base + i;
        if (idx < N_NODES) {
            rowptr[idx] = run;
            cursor[idx] = run;
            run += deg[idx];
        }
    }
    if (t == 255) rowptr[N_NODES] = run;
}

// also records dst node per CSR slot so edge weights can be computed CSR-ordered
__global__ __launch_bounds__(256) void scatter_kernel(const int* __restrict__ src,
                                                      const int* __restrict__ dst,
                                                      int* __restrict__ cursor,
                                                      int* __restrict__ csr,
                                                      int* __restrict__ dnd) {
    int e = blockIdx.x * 256 + threadIdx.x;
    if (e < E_EDGES) {
        int dn = dst[e];
        int p = atomicAdd(&cursor[dn], 1);
        csr[p] = src[e];
        dnd[p] = dn;
    }
}

// ---------------- per-edge (and self-loop) attention weights ----------------
__global__ __launch_bounds__(256) void eweight_kernel(const int* __restrict__ csr,
                                                      const int* __restrict__ dnd,
                                                      const float* __restrict__ s,
                                                      const float* __restrict__ d,
                                                      float* __restrict__ w4,
                                                      float* __restrict__ wself) {
    int p = blockIdx.x * 256 + threadIdx.x;
    if (p >= E_EDGES + N_NODES) return;
    int sn, dn;
    float* outp;
    if (p < E_EDGES) {
        sn = csr[p];
        dn = dnd[p];
        outp = w4 + 4 * (size_t)p;
    } else {
        sn = p - E_EDGES;
        dn = sn;
        outp = wself + 4 * (size_t)sn;
    }
    float4 sv = *(const float4*)(s + 4 * (size_t)sn);
    float4 dv = *(const float4*)(d + 4 * (size_t)dn);
    float4 wv;
    float e;
    e = sv.x + dv.x; e = e > 0.f ? e : SLOPE * e; wv.x = expf(e);
    e = sv.y + dv.y; e = e > 0.f ? e : SLOPE * e; wv.y = expf(e);
    e = sv.z + dv.z; e = e > 0.f ? e : SLOPE * e; wv.z = expf(e);
    e = sv.w + dv.w; e = e > 0.f ? e : SLOPE * e; wv.w = expf(e);
    *(float4*)outp = wv;
}

// ---------------- GEMM: 64x64 tile, 4x4 micro-tile, reg-prefetch, dual-output merge ----
// out = A[M,K] * [W0;W1][NO,K]^T. Columns [0,split) -> out0 (MODE0), [split,NO) -> out1 (MODE1).
// MODE: 0 raw, 1 softplus(v+b), 2 clip(softplus(v+b),0.1,1000), 3 max(softplus(v+b),RMIN)
// TRANS: write out[col*M + row] ([NO, M] layout)
template <int MODE, bool TRANS>
__device__ __forceinline__ void gemm_epilogue4(const float acc[4][4],
                                               const float* __restrict__ bp,
                                               float* __restrict__ op,
                                               int ow, int colbase, int r0, int lc, int M) {
    float bv[4] = {0.f, 0.f, 0.f, 0.f};
    if (MODE != 0) *(float4*)bv = *(const float4*)(bp + colbase + lc);
    float vals[4][4];
#pragma unroll
    for (int i = 0; i < 4; ++i)
#pragma unroll
        for (int j = 0; j < 4; ++j) {
            float v = acc[i][j];
            if (MODE == 1) v = softplus_f(v + bv[j]);
            else if (MODE == 2) { v = softplus_f(v + bv[j]); v = fminf(fmaxf(v, 0.1f), 1000.0f); }
            else if (MODE == 3) { v = fmaxf(softplus_f(v + bv[j]), RMIN); }
            vals[i][j] = v;
        }
    if (!TRANS) {
#pragma unroll
        for (int i = 0; i < 4; ++i) {
            int row = r0 + i;
            if (row < M) *(float4*)(op + (size_t)row * ow + colbase + lc) = *(float4*)vals[i];
        }
    } else {
        if (r0 + 3 < M) {
#pragma unroll
            for (int j = 0; j < 4; ++j) {
                int c = colbase + lc + j;
                float col[4] = {vals[0][j], vals[1][j], vals[2][j], vals[3][j]};
                *(float4*)(op + (size_t)c * M + r0) = *(float4*)col;
            }
        } else {
#pragma unroll
            for (int i = 0; i < 4; ++i) {
                int row = r0 + i;
                if (row < M)
#pragma unroll
                    for (int j = 0; j < 4; ++j) op[(size_t)(colbase + lc + j) * M + row] = vals[i][j];
            }
        }
    }
}

template <int MODE0, int MODE1, bool TRANS>
__global__ __launch_bounds__(256) void gemm64_kernel(const float* __restrict__ A,
                                                     const float* __restrict__ W0,
                                                     const float* __restrict__ W1,
                                                     const float* __restrict__ b0p,
                                                     const float* __restrict__ b1p,
                                                     float* __restrict__ out0,
                                                     float* __restrict__ out1,
                                                     int M, int K, int split, int no1) {
    __shared__ float As[16][68];
    __shared__ float Bs[16][68];
    int tid = threadIdx.x;
    int tx = tid & 15, ty = tid >> 4;
    int bm = blockIdx.x * 64;
    int bn = blockIdx.y * 64;
    bool first = bn < split;
    const float* W = first ? (W0 + (size_t)bn * K) : (W1 + (size_t)(bn - split) * K);
    int m = tid >> 2;            // 0..63 (A row within tile / B row within tile)
    int kk0 = (tid & 3) * 4;     // 0,4,8,12
    int arow = bm + m;
    bool avalid = arow < M;
    const float* Ap = A + (size_t)arow * K + kk0;
    const float* Wp = W + (size_t)m * K + kk0;

    // prefetch tile 0
    float4 av = make_float4(0.f, 0.f, 0.f, 0.f);
    if (avalid) av = *(const float4*)(Ap);
    float4 bv = *(const float4*)(Wp);

    float acc[4][4] = {};
    int T = K >> 4;
    for (int t = 0; t < T; ++t) {
        As[kk0 + 0][m] = av.x; As[kk0 + 1][m] = av.y;
        As[kk0 + 2][m] = av.z; As[kk0 + 3][m] = av.w;
        Bs[kk0 + 0][m] = bv.x; Bs[kk0 + 1][m] = bv.y;
        Bs[kk0 + 2][m] = bv.z; Bs[kk0 + 3][m] = bv.w;
        __syncthreads();
        // issue next tile's global loads early; latency hides under the FMA block
        if (t + 1 < T) {
            int ko = (t + 1) << 4;
            if (avalid) av = *(const float4*)(Ap + ko);
            bv = *(const float4*)(Wp + ko);
        }
#pragma unroll
        for (int kk = 0; kk < 16; ++kk) {
            float a[4], b[4];
            *(float4*)a = *(const float4*)(&As[kk][ty * 4]);
            *(float4*)b = *(const float4*)(&Bs[kk][tx * 4]);
#pragma unroll
            for (int i = 0; i < 4; ++i)
#pragma unroll
                for (int j = 0; j < 4; ++j) acc[i][j] += a[i] * b[j];
        }
        __syncthreads();
    }
    int r0 = bm + ty * 4;
    int lc = tx * 4;
    if (first) gemm_epilogue4<MODE0, TRANS>(acc, b0p, out0, split, bn, r0, lc, M);
    else       gemm_epilogue4<MODE1, TRANS>(acc, b1p, out1, no1, bn - split, r0, lc, M);
}

// ---------------- per-node attention logits s,d ----------------
template <int F, int CPER>
__global__ __launch_bounds__(256) void sd_kernel(const float* __restrict__ xw,
                                                 const float* __restrict__ asrc,
                                                 const float* __restrict__ adst,
                                                 float* __restrict__ s,
                                                 float* __restrict__ d) {
    int wave = threadIdx.x >> 6;
    int lane = threadIdx.x & 63;
    int n = blockIdx.x * 4 + wave;
    if (n >= N_NODES) return;
    float ss[NHEADS] = {0, 0, 0, 0}, dd[NHEADS] = {0, 0, 0, 0};
#pragma unroll
    for (int j = 0; j < F / 64; ++j) {
        int c = j * 64 + lane;
        int h = c / CPER;
        int cc = c % CPER;
        float v = xw[(size_t)n * F + c];
        ss[h] += v * asrc[h * CPER + cc];
        dd[h] += v * adst[h * CPER + cc];
    }
#pragma unroll
    for (int off = 32; off > 0; off >>= 1) {
#pragma unroll
        for (int h = 0; h < NHEADS; ++h) {
            ss[h] += __shfl_xor(ss[h], off, 64);
            dd[h] += __shfl_xor(dd[h], off, 64);
        }
    }
    if (lane == 0) {
#pragma unroll
        for (int h = 0; h < NHEADS; ++h) {
            s[n * NHEADS + h] = ss[h];
            d[n * NHEADS + h] = dd[h];
        }
    }
}

// per-head weight select: compile-time for CPER=64 (h==j), cndmask on lane bit 5 for CPER=32
template <int CPER>
__device__ __forceinline__ float pick_w(float4 w, int j, int lane) {
    if constexpr (CPER == 64) {
        return j == 0 ? w.x : (j == 1 ? w.y : (j == 2 ? w.z : w.w));
    } else {
        float lo = (j == 0) ? w.x : w.z;
        float hi = (j == 0) ? w.y : w.w;
        return (lane & 32) ? hi : lo;
    }
}

// ---------------- GAT aggregation: one wave per node, precomputed weights ----------------
template <int F, int CPER>
__global__ __launch_bounds__(256) void agg_kernel(const float* __restrict__ xw,
                                                  const int* __restrict__ rowptr,
                                                  const int* __restrict__ csr,
                                                  const float* __restrict__ w4,
                                                  const float* __restrict__ wself,
                                                  const float* __restrict__ bias,
                                                  float* __restrict__ out) {
    int wave = threadIdx.x >> 6;
    int lane = threadIdx.x & 63;
    int n = blockIdx.x * 4 + wave;
    if (n >= N_NODES) return;
    constexpr int J = F / 64;

    float4 wl = *(const float4*)(wself + 4 * (size_t)n);
    float den[NHEADS] = {wl.x, wl.y, wl.z, wl.w};
    float acc[J];
#pragma unroll
    for (int j = 0; j < J; ++j) {
        int c = j * 64 + lane;
        acc[j] = pick_w<CPER>(wl, j, lane) * xw[(size_t)n * F + c];
    }

    int beg = rowptr[n], end = rowptr[n + 1];
    int idx = beg;
    for (; idx + 2 <= end; idx += 2) {
        int sa = csr[idx], sb = csr[idx + 1];
        float4 wa = *(const float4*)(w4 + 4 * (size_t)idx);
        float4 wb = *(const float4*)(w4 + 4 * (size_t)(idx + 1));
        den[0] += wa.x + wb.x;
        den[1] += wa.y + wb.y;
        den[2] += wa.z + wb.z;
        den[3] += wa.w + wb.w;
        const float* ra = xw + (size_t)sa * F;
        const float* rb = xw + (size_t)sb * F;
#pragma unroll
        for (int j = 0; j < J; ++j) {
            int c = j * 64 + lane;
            acc[j] += pick_w<CPER>(wa, j, lane) * ra[c];
            acc[j] += pick_w<CPER>(wb, j, lane) * rb[c];
        }
    }
    if (idx < end) {
        int sa = csr[idx];
        float4 wa = *(const float4*)(w4 + 4 * (size_t)idx);
        den[0] += wa.x;
        den[1] += wa.y;
        den[2] += wa.z;
        den[3] += wa.w;
        const float* ra = xw + (size_t)sa * F;
#pragma unroll
        for (int j = 0; j < J; ++j) {
            int c = j * 64 + lane;
            acc[j] += pick_w<CPER>(wa, j, lane) * ra[c];
        }
    }

#pragma unroll
    for (int j = 0; j < J; ++j) {
        int c = j * 64 + lane;
        float dv;
        if constexpr (CPER == 64) dv = den[j];
        else dv = (lane & 32) ? den[2 * j + 1] : den[2 * j];
        out[(size_t)n * F + c] = acc[j] / (dv + 1e-16f) + bias[c];
    }
}

// ---------------- Weibull reparameterization ----------------
__global__ __launch_bounds__(256) void theta_kernel(const float* __restrict__ eps,
                                                    const float* __restrict__ kptr,
                                                    float* __restrict__ lptr,
                                                    float* __restrict__ theta, int ZN) {
    int i = blockIdx.x * 256 + threadIdx.x;
    if (i >= ZN) return;
    float k = kptr[i];
    float invk = 1.0f / k;
    float lg = expf(lgammaf(1.0f + invk));
    float l = lptr[i] / lg;
    lptr[i] = l;
    float acc = 0.0f;
#pragma unroll
    for (int ss = 0; ss < 10; ++ss) {
        float u = eps[(size_t)ss * ZN + i];
        float v = -logf(fmaxf(1.0f - u, RMIN));
        acc += exp2f(log2f(v) * invk);
    }
    float th = l * acc * 0.1f;
    th = fminf(fmaxf(th, RMIN), THETA_MAX);
    theta[i] = th;
}

extern "C" void kernel_launch(void* const* d_in, const int* in_sizes, int n_in,
                              void* d_out, int out_size, void* d_ws, size_t ws_size,
                              hipStream_t stream) {
    const float* x     = (const float*)d_in[0];
    const int*   eidx  = (const int*)d_in[1];
    const float* gatW0 = (const float*)d_in[2];
    const float* asrc0 = (const float*)d_in[3];
    const float* adst0 = (const float*)d_in[4];
    const float* gatb0 = (const float*)d_in[5];
    const float* fcW0  = (const float*)d_in[6];
    const float* fcb0  = (const float*)d_in[7];
    const float* shW0  = (const float*)d_in[8];
    const float* shb0  = (const float*)d_in[9];
    const float* scW0  = (const float*)d_in[10];
    const float* scb0  = (const float*)d_in[11];
    const float* gatW1 = (const float*)d_in[12];
    const float* asrc1 = (const float*)d_in[13];
    const float* adst1 = (const float*)d_in[14];
    const float* gatb1 = (const float*)d_in[15];
    const float* fcW1  = (const float*)d_in[16];
    const float* fcb1  = (const float*)d_in[17];
    const float* shW1  = (const float*)d_in[18];
    const float* shb1  = (const float*)d_in[19];
    const float* scW1  = (const float*)d_in[20];
    const float* scb1  = (const float*)d_in[21];
    const float* eps0  = (const float*)d_in[22];
    const float* eps1  = (const float*)d_in[23];

    const int* e_src = eidx;
    const int* e_dst = eidx + E_EDGES;

    // workspace carve-up
    size_t off = 0;
    auto carve = [&](size_t elems) {
        void* p = (char*)d_ws + off;
        off += ((elems * 4 + 255) / 256) * 256;
        return p;
    };
    float* xw0 = (float*)carve(20000u * 256);
    float* h0  = (float*)carve(20000u * 256);
    float* z0  = (float*)carve(20000u * 128);
    float* xw1 = (float*)carve(20000u * 128);
    float* h1  = (float*)carve(20000u * 128);
    float* z1  = (float*)carve(20000u * 64);
    float* s0  = (float*)carve(20000u * 4);
    float* d0  = (float*)carve(20000u * 4);
    float* s1  = (float*)carve(20000u * 4);
    float* d1  = (float*)carve(20000u * 4);
    int* deg    = (int*)carve(20000);
    int* rowptr = (int*)carve(20001);
    int* cursor = (int*)carve(20000);
    int* csr    = (int*)carve(E_EDGES);
    int* dnd    = (int*)carve(E_EDGES);
    float* w4    = (float*)carve((size_t)E_EDGES * 4);  // reused across both layers
    float* wself = (float*)carve(20000u * 4);

    float* out    = (float*)d_out;
    float* theta0 = out;
    float* theta1 = out + 2560000;
    float* k0     = out + 3840000;
    float* k1     = out + 6400000;
    float* l0     = out + 7680000;
    float* l1     = out + 10240000;

    const int M = N_NODES;
    dim3 blk(256);
    const int GX = (N_NODES + 63) / 64;  // 313
    const int EW_BLOCKS = (E_EDGES + N_NODES + 255) / 256;

    // CSR build
    (void)hipMemsetAsync(deg, 0, N_NODES * sizeof(int), stream);
    count_kernel<<<(E_EDGES + 255) / 256, blk, 0, stream>>>(e_dst, deg);
    scan_kernel<<<1, blk, 0, stream>>>(deg, rowptr, cursor);
    scatter_kernel<<<(E_EDGES + 255) / 256, blk, 0, stream>>>(e_src, e_dst, cursor, csr, dnd);

    // layer 0: xw0 = x @ gatW0^T
    gemm64_kernel<0, 0, false><<<dim3(GX, 4), blk, 0, stream>>>(
        x, gatW0, nullptr, nullptr, nullptr, xw0, nullptr, M, 256, 256, 0);
    sd_kernel<256, 64><<<5000, blk, 0, stream>>>(xw0, asrc0, adst0, s0, d0);
    eweight_kernel<<<EW_BLOCKS, blk, 0, stream>>>(csr, dnd, s0, d0, w4, wself);
    agg_kernel<256, 64><<<5000, blk, 0, stream>>>(xw0, rowptr, csr, w4, wself, gatb0, h0);

    // merged: z0 = softplus(h0 @ fcW0^T + b) | xw1 = h0 @ gatW1^T
    gemm64_kernel<1, 0, false><<<dim3(GX, 4), blk, 0, stream>>>(
        h0, fcW0, gatW1, fcb0, nullptr, z0, xw1, M, 256, 128, 128);

    // layer 1
    sd_kernel<128, 32><<<5000, blk, 0, stream>>>(xw1, asrc1, adst1, s1, d1);
    eweight_kernel<<<EW_BLOCKS, blk, 0, stream>>>(csr, dnd, s1, d1, w4, wself);
    agg_kernel<128, 32><<<5000, blk, 0, stream>>>(xw1, rowptr, csr, w4, wself, gatb1, h1);
    gemm64_kernel<1, 0, false><<<dim3(GX, 1), blk, 0, stream>>>(
        h1, fcW1, nullptr, fcb1, nullptr, z1, nullptr, M, 128, 64, 0);

    // merged heads (transposed [z, N] into d_out): k = clip(sp(.)), l = max(sp(.), RMIN)
    gemm64_kernel<2, 3, true><<<dim3(GX, 4), blk, 0, stream>>>(
        z0, shW0, scW0, shb0, scb0, k0, l0, M, 128, 128, 128);
    gemm64_kernel<2, 3, true><<<dim3(GX, 2), blk, 0, stream>>>(
        z1, shW1, scW1, shb1, scb1, k1, l1, M, 64, 64, 64);

    // reparameterize (finalizes l in-place, writes theta)
    theta_kernel<<<(2560000 + 255) / 256, blk, 0, stream>>>(eps0, k0, l0, theta0, 2560000);
    theta_kernel<<<(1280000 + 255) / 256, blk, 0, stream>>>(eps1, k1, l1, theta1, 1280000);
}

// Round 4
// 620.023 us; speedup vs baseline: 1.1032x; 1.0102x over previous
//
#include <hip/hip_runtime.h>
#include <math.h>

#define N_NODES 20000
#define E_EDGES 320000
#define NHEADS 4
#define RMIN 2.2e-10f
#define THETA_MAX 1000.0f
#define SLOPE 0.2f

__device__ __forceinline__ float softplus_f(float x) {
    // log(1+exp(x)), stable; matches jax.nn.softplus
    return fmaxf(x, 0.0f) + log1pf(expf(-fabsf(x)));
}

// exp(leaky_relu(s+d)) for 4 heads at once
__device__ __forceinline__ float4 edge_w(float4 sv, float4 dv) {
    float4 w;
    float e;
    e = sv.x + dv.x; e = e > 0.f ? e : SLOPE * e; w.x = expf(e);
    e = sv.y + dv.y; e = e > 0.f ? e : SLOPE * e; w.y = expf(e);
    e = sv.z + dv.z; e = e > 0.f ? e : SLOPE * e; w.z = expf(e);
    e = sv.w + dv.w; e = e > 0.f ? e : SLOPE * e; w.w = expf(e);
    return w;
}

// ---------------- CSR build ----------------
__global__ __launch_bounds__(256) void count_kernel(const int* __restrict__ dst,
                                                    int* __restrict__ deg) {
    int e = blockIdx.x * 256 + threadIdx.x;
    if (e < E_EDGES) atomicAdd(&deg[dst[e]], 1);
}

__global__ __launch_bounds__(256) void scan_kernel(const int* __restrict__ deg,
                                                   int* __restrict__ rowptr,
                                                   int* __restrict__ cursor) {
    __shared__ int part[256];
    int t = threadIdx.x;
    const int CH = (N_NODES + 255) / 256;  // 79
    int base = t * CH;
    int sum = 0;
    for (int i = 0; i < CH; ++i) {
        int idx = base + i;
        if (idx < N_NODES) sum += deg[idx];
    }
    part[t] = sum;
    __syncthreads();
    // Hillis-Steele inclusive scan
    for (int off = 1; off < 256; off <<= 1) {
        int v = (t >= off) ? part[t - off] : 0;
        __syncthreads();
        part[t] += v;
        __syncthreads();
    }
    int run = (t == 0) ? 0 : part[t - 1];
    for (int i = 0; i < CH; ++i) {
        int idx = base + i;
        if (idx < N_NODES) {
            rowptr[idx] = run;
            cursor[idx] = run;
            run += deg[idx];
        }
    }
    if (t == 255) rowptr[N_NODES] = run;
}

__global__ __launch_bounds__(256) void scatter_kernel(const int* __restrict__ src,
                                                      const int* __restrict__ dst,
                                                      int* __restrict__ cursor,
                                                      int* __restrict__ csr) {
    int e = blockIdx.x * 256 + threadIdx.x;
    if (e < E_EDGES) {
        int p = atomicAdd(&cursor[dst[e]], 1);
        csr[p] = src[e];
    }
}

// ---------------- GEMM: 64x64 tile, 4x4 micro-tile, reg-prefetch ----------------
// out = A[M,K] * [W0;W1][NO,K]^T. Columns [0,split) -> out0 (MODE0), [split,NO) -> out1 (MODE1).
// MODE: 0 raw, 1 softplus(v+b), 2 clip(softplus(v+b),0.1,1000), 3 max(softplus(v+b),RMIN)
// TRANS: write out[col*M + row]. SDW: 0 none, 1 fused s/d on out0 cols, 2 on out1 cols.
// s/d fusion exploits head-span (CPER) alignment with 64-col tiles: full in-block reduction,
// direct stores, no atomics, no pre-zeroing.
template <int MODE, bool TRANS>
__device__ __forceinline__ void gemm_epilogue4(const float acc[4][4],
                                               const float* __restrict__ bp,
                                               float* __restrict__ op,
                                               int ow, int colbase, int r0, int lc, int M) {
    float bv[4] = {0.f, 0.f, 0.f, 0.f};
    if (MODE != 0) *(float4*)bv = *(const float4*)(bp + colbase + lc);
    float vals[4][4];
#pragma unroll
    for (int i = 0; i < 4; ++i)
#pragma unroll
        for (int j = 0; j < 4; ++j) {
            float v = acc[i][j];
            if (MODE == 1) v = softplus_f(v + bv[j]);
            else if (MODE == 2) { v = softplus_f(v + bv[j]); v = fminf(fmaxf(v, 0.1f), 1000.0f); }
            else if (MODE == 3) { v = fmaxf(softplus_f(v + bv[j]), RMIN); }
            vals[i][j] = v;
        }
    if (!TRANS) {
#pragma unroll
        for (int i = 0; i < 4; ++i) {
            int row = r0 + i;
            if (row < M) *(float4*)(op + (size_t)row * ow + colbase + lc) = *(float4*)vals[i];
        }
    } else {
        if (r0 + 3 < M) {
#pragma unroll
            for (int j = 0; j < 4; ++j) {
                int c = colbase + lc + j;
                float col[4] = {vals[0][j], vals[1][j], vals[2][j], vals[3][j]};
                *(float4*)(op + (size_t)c * M + r0) = *(float4*)col;
            }
        } else {
#pragma unroll
            for (int i = 0; i < 4; ++i) {
                int row = r0 + i;
                if (row < M)
#pragma unroll
                    for (int j = 0; j < 4; ++j) op[(size_t)(colbase + lc + j) * M + row] = vals[i][j];
            }
        }
    }
}

template <int MODE0, int MODE1, bool TRANS, int SDW, int CPER>
__global__ __launch_bounds__(256) void gemm64_kernel(const float* __restrict__ A,
                                                     const float* __restrict__ W0,
                                                     const float* __restrict__ W1,
                                                     const float* __restrict__ b0p,
                                                     const float* __restrict__ b1p,
                                                     float* __restrict__ out0,
                                                     float* __restrict__ out1,
                                                     const float* __restrict__ asrc,
                                                     const float* __restrict__ adst,
                                                     float* __restrict__ sp,
                                                     float* __restrict__ dp,
                                                     int M, int K, int split, int no1) {
    __shared__ float As[16][68];
    __shared__ float Bs[16][68];
    int tid = threadIdx.x;
    int tx = tid & 15, ty = tid >> 4;
    int bm = blockIdx.x * 64;
    int bn = blockIdx.y * 64;
    bool first = bn < split;
    const float* W = first ? (W0 + (size_t)bn * K) : (W1 + (size_t)(bn - split) * K);
    int m = tid >> 2;            // 0..63
    int kk0 = (tid & 3) * 4;     // 0,4,8,12
    int arow = bm + m;
    bool avalid = arow < M;
    const float* Ap = A + (size_t)arow * K + kk0;
    const float* Wp = W + (size_t)m * K + kk0;

    float4 av = make_float4(0.f, 0.f, 0.f, 0.f);
    if (avalid) av = *(const float4*)(Ap);
    float4 bv = *(const float4*)(Wp);

    float acc[4][4] = {};
    int T = K >> 4;
    for (int t = 0; t < T; ++t) {
        As[kk0 + 0][m] = av.x; As[kk0 + 1][m] = av.y;
        As[kk0 + 2][m] = av.z; As[kk0 + 3][m] = av.w;
        Bs[kk0 + 0][m] = bv.x; Bs[kk0 + 1][m] = bv.y;
        Bs[kk0 + 2][m] = bv.z; Bs[kk0 + 3][m] = bv.w;
        __syncthreads();
        if (t + 1 < T) {
            int ko = (t + 1) << 4;
            if (avalid) av = *(const float4*)(Ap + ko);
            bv = *(const float4*)(Wp + ko);
        }
#pragma unroll
        for (int kk = 0; kk < 16; ++kk) {
            float a[4], b[4];
            *(float4*)a = *(const float4*)(&As[kk][ty * 4]);
            *(float4*)b = *(const float4*)(&Bs[kk][tx * 4]);
#pragma unroll
            for (int i = 0; i < 4; ++i)
#pragma unroll
                for (int j = 0; j < 4; ++j) acc[i][j] += a[i] * b[j];
        }
        __syncthreads();
    }
    int r0 = bm + ty * 4;
    int lc = tx * 4;

    // fused attention-logit reduction on RAW acc (the sd cols are always MODE 0 / raw)
    if constexpr (SDW != 0) {
        bool dosd = (SDW == 1) ? first : !first;
        if (dosd) {
            int bo = (SDW == 1) ? bn : bn - split;  // column offset within the xw feature dim
            float4 as4 = *(const float4*)(asrc + bo + lc);
            float4 ad4 = *(const float4*)(adst + bo + lc);
            float ps[4], pd[4];
#pragma unroll
            for (int i = 0; i < 4; ++i) {
                ps[i] = acc[i][0] * as4.x + acc[i][1] * as4.y + acc[i][2] * as4.z + acc[i][3] * as4.w;
                pd[i] = acc[i][0] * ad4.x + acc[i][1] * ad4.y + acc[i][2] * ad4.z + acc[i][3] * ad4.w;
            }
            // reduce across tx group: full 16 lanes (CPER=64) or two 8-lane halves (CPER=32)
#pragma unroll
            for (int off = (CPER == 64 ? 8 : 4); off >= 1; off >>= 1) {
#pragma unroll
                for (int i = 0; i < 4; ++i) {
                    ps[i] += __shfl_xor(ps[i], off, 64);
                    pd[i] += __shfl_xor(pd[i], off, 64);
                }
            }
            bool lanesel;
            int h;
            if constexpr (CPER == 64) { lanesel = (tx == 0); h = bo >> 6; }
            else { lanesel = ((tx & 7) == 0); h = (bo >> 5) + (tx >> 3); }
            if (lanesel) {
#pragma unroll
                for (int i = 0; i < 4; ++i) {
                    int row = r0 + i;
                    if (row < M) {
                        sp[row * NHEADS + h] = ps[i];
                        dp[row * NHEADS + h] = pd[i];
                    }
                }
            }
        }
    }

    if (first) gemm_epilogue4<MODE0, TRANS>(acc, b0p, out0, split, bn, r0, lc, M);
    else       gemm_epilogue4<MODE1, TRANS>(acc, b1p, out1, no1, bn - split, r0, lc, M);
}

// ---------------- merged tail GEMM: y=0 -> z1 = sp(h1@fcW1^T+b); y=1..4 -> k0/l0 heads ----
__global__ __launch_bounds__(256) void gemmC_kernel(const float* __restrict__ h1,
                                                    const float* __restrict__ fcW1,
                                                    const float* __restrict__ fcb1,
                                                    float* __restrict__ z1,
                                                    const float* __restrict__ z0,
                                                    const float* __restrict__ shW0,
                                                    const float* __restrict__ shb0,
                                                    float* __restrict__ k0,
                                                    const float* __restrict__ scW0,
                                                    const float* __restrict__ scb0,
                                                    float* __restrict__ l0,
                                                    int M) {
    constexpr int K = 128;
    __shared__ float As[16][68];
    __shared__ float Bs[16][68];
    int tid = threadIdx.x;
    int tx = tid & 15, ty = tid >> 4;
    int bm = blockIdx.x * 64;
    int y = blockIdx.y;
    const float* A;
    const float* W;
    if (y == 0)      { A = h1; W = fcW1; }
    else if (y <= 2) { A = z0; W = shW0 + (size_t)(y - 1) * 64 * K; }
    else             { A = z0; W = scW0 + (size_t)(y - 3) * 64 * K; }
    int m = tid >> 2;
    int kk0 = (tid & 3) * 4;
    int arow = bm + m;
    bool avalid = arow < M;
    const float* Ap = A + (size_t)arow * K + kk0;
    const float* Wp = W + (size_t)m * K + kk0;

    float4 av = make_float4(0.f, 0.f, 0.f, 0.f);
    if (avalid) av = *(const float4*)(Ap);
    float4 bv = *(const float4*)(Wp);

    float acc[4][4] = {};
    constexpr int T = K >> 4;
    for (int t = 0; t < T; ++t) {
        As[kk0 + 0][m] = av.x; As[kk0 + 1][m] = av.y;
        As[kk0 + 2][m] = av.z; As[kk0 + 3][m] = av.w;
        Bs[kk0 + 0][m] = bv.x; Bs[kk0 + 1][m] = bv.y;
        Bs[kk0 + 2][m] = bv.z; Bs[kk0 + 3][m] = bv.w;
        __syncthreads();
        if (t + 1 < T) {
            int ko = (t + 1) << 4;
            if (avalid) av = *(const float4*)(Ap + ko);
            bv = *(const float4*)(Wp + ko);
        }
#pragma unroll
        for (int kk = 0; kk < 16; ++kk) {
            float a[4], b[4];
            *(float4*)a = *(const float4*)(&As[kk][ty * 4]);
            *(float4*)b = *(const float4*)(&Bs[kk][tx * 4]);
#pragma unroll
            for (int i = 0; i < 4; ++i)
#pragma unroll
                for (int j = 0; j < 4; ++j) acc[i][j] += a[i] * b[j];
        }
        __syncthreads();
    }
    int r0 = bm + ty * 4;
    int lc = tx * 4;
    if (y == 0)      gemm_epilogue4<1, false>(acc, fcb1, z1, 64, 0, r0, lc, M);
    else if (y <= 2) gemm_epilogue4<2, true>(acc, shb0, k0, 128, (y - 1) * 64, r0, lc, M);
    else             gemm_epilogue4<3, true>(acc, scb0, l0, 128, (y - 3) * 64, r0, lc, M);
}

// per-head weight select: compile-time for CPER=64 (h==j), cndmask on lane bit 5 for CPER=32
template <int CPER>
__device__ __forceinline__ float pick_w(float4 w, int j, int lane) {
    if constexpr (CPER == 64) {
        return j == 0 ? w.x : (j == 1 ? w.y : (j == 2 ? w.z : w.w));
    } else {
        float lo = (j == 0) ? w.x : w.z;
        float hi = (j == 0) ? w.y : w.w;
        return (lane & 32) ? hi : lo;
    }
}

// ---------------- GAT aggregation: one wave per node, inline edge weights ----------------
// Each CSR slot is consumed exactly once, so the exp(leaky(.)) per edge is computed inline
// (4 wave-wide VALU exps per edge, ~4us total) instead of a separate kernel + memory roundtrip.
template <int F, int CPER>
__global__ __launch_bounds__(256) void agg_kernel(const float* __restrict__ xw,
                                                  const int* __restrict__ rowptr,
                                                  const int* __restrict__ csr,
                                                  const float* __restrict__ s,
                                                  const float* __restrict__ d,
                                                  const float* __restrict__ bias,
                                                  float* __restrict__ out) {
    int wave = threadIdx.x >> 6;
    int lane = threadIdx.x & 63;
    int n = blockIdx.x * 4 + wave;
    if (n >= N_NODES) return;
    constexpr int J = F / 64;

    float4 d4 = *(const float4*)(d + 4 * (size_t)n);
    float4 s4 = *(const float4*)(s + 4 * (size_t)n);
    float4 wl = edge_w(s4, d4);  // self-loop weight
    float den[NHEADS] = {wl.x, wl.y, wl.z, wl.w};
    float acc[J];
#pragma unroll
    for (int j = 0; j < J; ++j) {
        int c = j * 64 + lane;
        acc[j] = pick_w<CPER>(wl, j, lane) * xw[(size_t)n * F + c];
    }

    int beg = rowptr[n], end = rowptr[n + 1];
    int idx = beg;
    for (; idx + 2 <= end; idx += 2) {
        int sa = csr[idx], sb = csr[idx + 1];
        float4 wa = edge_w(*(const float4*)(s + 4 * (size_t)sa), d4);
        float4 wb = edge_w(*(const float4*)(s + 4 * (size_t)sb), d4);
        den[0] += wa.x + wb.x;
        den[1] += wa.y + wb.y;
        den[2] += wa.z + wb.z;
        den[3] += wa.w + wb.w;
        const float* ra = xw + (size_t)sa * F;
        const float* rb = xw + (size_t)sb * F;
#pragma unroll
        for (int j = 0; j < J; ++j) {
            int c = j * 64 + lane;
            acc[j] += pick_w<CPER>(wa, j, lane) * ra[c];
            acc[j] += pick_w<CPER>(wb, j, lane) * rb[c];
        }
    }
    if (idx < end) {
        int sa = csr[idx];
        float4 wa = edge_w(*(const float4*)(s + 4 * (size_t)sa), d4);
        den[0] += wa.x;
        den[1] += wa.y;
        den[2] += wa.z;
        den[3] += wa.w;
        const float* ra = xw + (size_t)sa * F;
#pragma unroll
        for (int j = 0; j < J; ++j) {
            int c = j * 64 + lane;
            acc[j] += pick_w<CPER>(wa, j, lane) * ra[c];
        }
    }

#pragma unroll
    for (int j = 0; j < J; ++j) {
        int c = j * 64 + lane;
        float dv;
        if constexpr (CPER == 64) dv = den[j];
        else dv = (lane & 32) ? den[2 * j + 1] : den[2 * j];
        out[(size_t)n * F + c] = acc[j] / (dv + 1e-16f) + bias[c];
    }
}

// ---------------- Weibull reparameterization, both z-levels in one launch ----------------
__device__ __forceinline__ void theta_work(const float* __restrict__ eps,
                                           const float* __restrict__ kptr,
                                           float* __restrict__ lptr,
                                           float* __restrict__ theta, int i, int ZN) {
    float k = kptr[i];
    float invk = 1.0f / k;
    float lg = expf(lgammaf(1.0f + invk));
    float l = lptr[i] / lg;
    lptr[i] = l;
    float acc = 0.0f;
#pragma unroll
    for (int ss = 0; ss < 10; ++ss) {
        float u = eps[(size_t)ss * ZN + i];
        float v = -logf(fmaxf(1.0f - u, RMIN));
        acc += exp2f(log2f(v) * invk);
    }
    float th = l * acc * 0.1f;
    th = fminf(fmaxf(th, RMIN), THETA_MAX);
    theta[i] = th;
}

__global__ __launch_bounds__(256) void theta2_kernel(const float* __restrict__ eps0,
                                                     float* __restrict__ k0,
                                                     float* __restrict__ l0,
                                                     float* __restrict__ th0,
                                                     const float* __restrict__ eps1,
                                                     float* __restrict__ k1,
                                                     float* __restrict__ l1,
                                                     float* __restrict__ th1) {
    int i = blockIdx.x * 256 + threadIdx.x;
    if (i < 2560000) {
        theta_work(eps0, k0, l0, th0, i, 2560000);
    } else {
        int j = i - 2560000;
        if (j < 1280000) theta_work(eps1, k1, l1, th1, j, 1280000);
    }
}

extern "C" void kernel_launch(void* const* d_in, const int* in_sizes, int n_in,
                              void* d_out, int out_size, void* d_ws, size_t ws_size,
                              hipStream_t stream) {
    const float* x     = (const float*)d_in[0];
    const int*   eidx  = (const int*)d_in[1];
    const float* gatW0 = (const float*)d_in[2];
    const float* asrc0 = (const float*)d_in[3];
    const float* adst0 = (const float*)d_in[4];
    const float* gatb0 = (const float*)d_in[5];
    const float* fcW0  = (const float*)d_in[6];
    const float* fcb0  = (const float*)d_in[7];
    const float* shW0  = (const float*)d_in[8];
    const float* shb0  = (const float*)d_in[9];
    const float* scW0  = (const float*)d_in[10];
    const float* scb0  = (const float*)d_in[11];
    const float* gatW1 = (const float*)d_in[12];
    const float* asrc1 = (const float*)d_in[13];
    const float* adst1 = (const float*)d_in[14];
    const float* gatb1 = (const float*)d_in[15];
    const float* fcW1  = (const float*)d_in[16];
    const float* fcb1  = (const float*)d_in[17];
    const float* shW1  = (const float*)d_in[18];
    const float* shb1  = (const float*)d_in[19];
    const float* scW1  = (const float*)d_in[20];
    const float* scb1  = (const float*)d_in[21];
    const float* eps0  = (const float*)d_in[22];
    const float* eps1  = (const float*)d_in[23];

    const int* e_src = eidx;
    const int* e_dst = eidx + E_EDGES;

    // workspace carve-up
    size_t off = 0;
    auto carve = [&](size_t elems) {
        void* p = (char*)d_ws + off;
        off += ((elems * 4 + 255) / 256) * 256;
        return p;
    };
    float* xw0 = (float*)carve(20000u * 256);
    float* h0  = (float*)carve(20000u * 256);
    float* z0  = (float*)carve(20000u * 128);
    float* xw1 = (float*)carve(20000u * 128);
    float* h1  = (float*)carve(20000u * 128);
    float* z1  = (float*)carve(20000u * 64);
    float* s0  = (float*)carve(20000u * 4);
    float* d0  = (float*)carve(20000u * 4);
    float* s1  = (float*)carve(20000u * 4);
    float* d1  = (float*)carve(20000u * 4);
    int* deg    = (int*)carve(20000);
    int* rowptr = (int*)carve(20001);
    int* cursor = (int*)carve(20000);
    int* csr    = (int*)carve(E_EDGES);

    float* out    = (float*)d_out;
    float* theta0 = out;
    float* theta1 = out + 2560000;
    float* k0     = out + 3840000;
    float* k1     = out + 6400000;
    float* l0     = out + 7680000;
    float* l1     = out + 10240000;

    const int M = N_NODES;
    dim3 blk(256);
    const int GX = (N_NODES + 63) / 64;  // 313

    // CSR build
    (void)hipMemsetAsync(deg, 0, N_NODES * sizeof(int), stream);
    count_kernel<<<(E_EDGES + 255) / 256, blk, 0, stream>>>(e_dst, deg);
    scan_kernel<<<1, blk, 0, stream>>>(deg, rowptr, cursor);
    scatter_kernel<<<(E_EDGES + 255) / 256, blk, 0, stream>>>(e_src, e_dst, cursor, csr);

    // layer 0: xw0 = x @ gatW0^T, fused s0/d0
    gemm64_kernel<0, 0, false, 1, 64><<<dim3(GX, 4), blk, 0, stream>>>(
        x, gatW0, nullptr, nullptr, nullptr, xw0, nullptr,
        asrc0, adst0, s0, d0, M, 256, 256, 0);
    agg_kernel<256, 64><<<5000, blk, 0, stream>>>(xw0, rowptr, csr, s0, d0, gatb0, h0);

    // merged: z0 = softplus(h0 @ fcW0^T + b) | xw1 = h0 @ gatW1^T, fused s1/d1 on xw1 cols
    gemm64_kernel<1, 0, false, 2, 32><<<dim3(GX, 4), blk, 0, stream>>>(
        h0, fcW0, gatW1, fcb0, nullptr, z0, xw1,
        asrc1, adst1, s1, d1, M, 256, 128, 128);
    agg_kernel<128, 32><<<5000, blk, 0, stream>>>(xw1, rowptr, csr, s1, d1, gatb1, h1);

    // merged tail: z1 gemm + z0-heads gemms (K=128 for all five y-tiles)
    gemmC_kernel<<<dim3(GX, 5), blk, 0, stream>>>(
        h1, fcW1, fcb1, z1, z0, shW0, shb0, k0, scW0, scb0, l0, M);

    // z1 heads (K=64): k1 = clip(sp(.)), l1 = max(sp(.), RMIN), transposed
    gemm64_kernel<2, 3, true, 0, 64><<<dim3(GX, 2), blk, 0, stream>>>(
        z1, shW1, scW1, shb1, scb1, k1, l1,
        nullptr, nullptr, nullptr, nullptr, M, 64, 64, 64);

    // reparameterize both levels (finalizes l in-place, writes theta)
    theta2_kernel<<<15000, blk, 0, stream>>>(eps0, k0, l0, theta0, eps1, k1, l1, theta1);
}

// Round 5
// 586.990 us; speedup vs baseline: 1.1653x; 1.0563x over previous
//
#include <hip/hip_runtime.h>
#include <math.h>

#define N_NODES 20000
#define E_EDGES 320000
#define NHEADS 4
#define RMIN 2.2e-10f
#define THETA_MAX 1000.0f
#define SLOPE 0.2f
#define LOG2E 1.4426950408889634f
#define LOG2_LN2 -0.5287663729448977f  /* log2(ln 2) */

__device__ __forceinline__ float softplus_f(float x) {
    // log(1+exp(x)), stable; matches jax.nn.softplus (libm path: feeds outputs k,l,z)
    return fmaxf(x, 0.0f) + log1pf(expf(-fabsf(x)));
}

// exp(leaky_relu(s+d)) for 4 heads at once — native v_exp_f32 (alpha ratios, ~1ulp)
__device__ __forceinline__ float4 edge_w(float4 sv, float4 dv) {
    float4 w;
    float e;
    e = (sv.x + dv.x) * LOG2E; e = e > 0.f ? e : SLOPE * e; w.x = __builtin_amdgcn_exp2f(e);
    e = (sv.y + dv.y) * LOG2E; e = e > 0.f ? e : SLOPE * e; w.y = __builtin_amdgcn_exp2f(e);
    e = (sv.z + dv.z) * LOG2E; e = e > 0.f ? e : SLOPE * e; w.z = __builtin_amdgcn_exp2f(e);
    e = (sv.w + dv.w) * LOG2E; e = e > 0.f ? e : SLOPE * e; w.w = __builtin_amdgcn_exp2f(e);
    return w;
}

// ---------------- CSR build ----------------
__global__ __launch_bounds__(256) void count_kernel(const int* __restrict__ dst,
                                                    int* __restrict__ deg) {
    int e = blockIdx.x * 256 + threadIdx.x;
    if (e < E_EDGES) atomicAdd(&deg[dst[e]], 1);
}

__global__ __launch_bounds__(256) void scan_kernel(const int* __restrict__ deg,
                                                   int* __restrict__ rowptr,
                                                   int* __restrict__ cursor) {
    __shared__ int part[256];
    int t = threadIdx.x;
    const int CH = (N_NODES + 255) / 256;  // 79
    int base = t * CH;
    int sum = 0;
    for (int i = 0; i < CH; ++i) {
        int idx = base + i;
        if (idx < N_NODES) sum += deg[idx];
    }
    part[t] = sum;
    __syncthreads();
    // Hillis-Steele inclusive scan
    for (int off = 1; off < 256; off <<= 1) {
        int v = (t >= off) ? part[t - off] : 0;
        __syncthreads();
        part[t] += v;
        __syncthreads();
    }
    int run = (t == 0) ? 0 : part[t - 1];
    for (int i = 0; i < CH; ++i) {
        int idx = base + i;
        if (idx < N_NODES) {
            rowptr[idx] = run;
            cursor[idx] = run;
            run += deg[idx];
        }
    }
    if (t == 255) rowptr[N_NODES] = run;
}

__global__ __launch_bounds__(256) void scatter_kernel(const int* __restrict__ src,
                                                      const int* __restrict__ dst,
                                                      int* __restrict__ cursor,
                                                      int* __restrict__ csr) {
    int e = blockIdx.x * 256 + threadIdx.x;
    if (e < E_EDGES) {
        int p = atomicAdd(&cursor[dst[e]], 1);
        csr[p] = src[e];
    }
}

// ---------------- GEMM: 64x64 tile, 4x4 micro-tile, reg-prefetch ----------------
// out = A[M,K] * [W0;W1][NO,K]^T. Columns [0,split) -> out0 (MODE0), [split,NO) -> out1 (MODE1).
// MODE: 0 raw, 1 softplus(v+b), 2 clip(softplus(v+b),0.1,1000), 3 max(softplus(v+b),RMIN)
// TRANS: write out[col*M + row]. SDW: 0 none, 1 fused s/d on out0 cols, 2 on out1 cols.
template <int MODE, bool TRANS>
__device__ __forceinline__ void gemm_epilogue4(const float acc[4][4],
                                               const float* __restrict__ bp,
                                               float* __restrict__ op,
                                               int ow, int colbase, int r0, int lc, int M) {
    float bv[4] = {0.f, 0.f, 0.f, 0.f};
    if (MODE != 0) *(float4*)bv = *(const float4*)(bp + colbase + lc);
    float vals[4][4];
#pragma unroll
    for (int i = 0; i < 4; ++i)
#pragma unroll
        for (int j = 0; j < 4; ++j) {
            float v = acc[i][j];
            if (MODE == 1) v = softplus_f(v + bv[j]);
            else if (MODE == 2) { v = softplus_f(v + bv[j]); v = fminf(fmaxf(v, 0.1f), 1000.0f); }
            else if (MODE == 3) { v = fmaxf(softplus_f(v + bv[j]), RMIN); }
            vals[i][j] = v;
        }
    if (!TRANS) {
#pragma unroll
        for (int i = 0; i < 4; ++i) {
            int row = r0 + i;
            if (row < M) *(float4*)(op + (size_t)row * ow + colbase + lc) = *(float4*)vals[i];
        }
    } else {
        if (r0 + 3 < M) {
#pragma unroll
            for (int j = 0; j < 4; ++j) {
                int c = colbase + lc + j;
                float col[4] = {vals[0][j], vals[1][j], vals[2][j], vals[3][j]};
                *(float4*)(op + (size_t)c * M + r0) = *(float4*)col;
            }
        } else {
#pragma unroll
            for (int i = 0; i < 4; ++i) {
                int row = r0 + i;
                if (row < M)
#pragma unroll
                    for (int j = 0; j < 4; ++j) op[(size_t)(colbase + lc + j) * M + row] = vals[i][j];
            }
        }
    }
}

template <int MODE0, int MODE1, bool TRANS, int SDW, int CPER>
__global__ __launch_bounds__(256) void gemm64_kernel(const float* __restrict__ A,
                                                     const float* __restrict__ W0,
                                                     const float* __restrict__ W1,
                                                     const float* __restrict__ b0p,
                                                     const float* __restrict__ b1p,
                                                     float* __restrict__ out0,
                                                     float* __restrict__ out1,
                                                     const float* __restrict__ asrc,
                                                     const float* __restrict__ adst,
                                                     float* __restrict__ sp,
                                                     float* __restrict__ dp,
                                                     int M, int K, int split, int no1) {
    __shared__ float As[16][68];
    __shared__ float Bs[16][68];
    int tid = threadIdx.x;
    int tx = tid & 15, ty = tid >> 4;
    int bm = blockIdx.x * 64;
    int bn = blockIdx.y * 64;
    bool first = bn < split;
    const float* W = first ? (W0 + (size_t)bn * K) : (W1 + (size_t)(bn - split) * K);
    int m = tid >> 2;            // 0..63
    int kk0 = (tid & 3) * 4;     // 0,4,8,12
    int arow = bm + m;
    bool avalid = arow < M;
    const float* Ap = A + (size_t)arow * K + kk0;
    const float* Wp = W + (size_t)m * K + kk0;

    float4 av = make_float4(0.f, 0.f, 0.f, 0.f);
    if (avalid) av = *(const float4*)(Ap);
    float4 bv = *(const float4*)(Wp);

    float acc[4][4] = {};
    int T = K >> 4;
    for (int t = 0; t < T; ++t) {
        As[kk0 + 0][m] = av.x; As[kk0 + 1][m] = av.y;
        As[kk0 + 2][m] = av.z; As[kk0 + 3][m] = av.w;
        Bs[kk0 + 0][m] = bv.x; Bs[kk0 + 1][m] = bv.y;
        Bs[kk0 + 2][m] = bv.z; Bs[kk0 + 3][m] = bv.w;
        __syncthreads();
        if (t + 1 < T) {
            int ko = (t + 1) << 4;
            if (avalid) av = *(const float4*)(Ap + ko);
            bv = *(const float4*)(Wp + ko);
        }
#pragma unroll
        for (int kk = 0; kk < 16; ++kk) {
            float a[4], b[4];
            *(float4*)a = *(const float4*)(&As[kk][ty * 4]);
            *(float4*)b = *(const float4*)(&Bs[kk][tx * 4]);
#pragma unroll
            for (int i = 0; i < 4; ++i)
#pragma unroll
                for (int j = 0; j < 4; ++j) acc[i][j] += a[i] * b[j];
        }
        __syncthreads();
    }
    int r0 = bm + ty * 4;
    int lc = tx * 4;

    // fused attention-logit reduction on RAW acc (the sd cols are always MODE 0 / raw)
    if constexpr (SDW != 0) {
        bool dosd = (SDW == 1) ? first : !first;
        if (dosd) {
            int bo = (SDW == 1) ? bn : bn - split;  // column offset within the xw feature dim
            float4 as4 = *(const float4*)(asrc + bo + lc);
            float4 ad4 = *(const float4*)(adst + bo + lc);
            float ps[4], pd[4];
#pragma unroll
            for (int i = 0; i < 4; ++i) {
                ps[i] = acc[i][0] * as4.x + acc[i][1] * as4.y + acc[i][2] * as4.z + acc[i][3] * as4.w;
                pd[i] = acc[i][0] * ad4.x + acc[i][1] * ad4.y + acc[i][2] * ad4.z + acc[i][3] * ad4.w;
            }
#pragma unroll
            for (int off = (CPER == 64 ? 8 : 4); off >= 1; off >>= 1) {
#pragma unroll
                for (int i = 0; i < 4; ++i) {
                    ps[i] += __shfl_xor(ps[i], off, 64);
                    pd[i] += __shfl_xor(pd[i], off, 64);
                }
            }
            bool lanesel;
            int h;
            if constexpr (CPER == 64) { lanesel = (tx == 0); h = bo >> 6; }
            else { lanesel = ((tx & 7) == 0); h = (bo >> 5) + (tx >> 3); }
            if (lanesel) {
#pragma unroll
                for (int i = 0; i < 4; ++i) {
                    int row = r0 + i;
                    if (row < M) {
                        sp[row * NHEADS + h] = ps[i];
                        dp[row * NHEADS + h] = pd[i];
                    }
                }
            }
        }
    }

    if (first) gemm_epilogue4<MODE0, TRANS>(acc, b0p, out0, split, bn, r0, lc, M);
    else       gemm_epilogue4<MODE1, TRANS>(acc, b1p, out1, no1, bn - split, r0, lc, M);
}

// ---------------- merged tail GEMM: y=0 -> z1 = sp(h1@fcW1^T+b); y=1..4 -> k0/l0 heads ----
__global__ __launch_bounds__(256) void gemmC_kernel(const float* __restrict__ h1,
                                                    const float* __restrict__ fcW1,
                                                    const float* __restrict__ fcb1,
                                                    float* __restrict__ z1,
                                                    const float* __restrict__ z0,
                                                    const float* __restrict__ shW0,
                                                    const float* __restrict__ shb0,
                                                    float* __restrict__ k0,
                                                    const float* __restrict__ scW0,
                                                    const float* __restrict__ scb0,
                                                    float* __restrict__ l0,
                                                    int M) {
    constexpr int K = 128;
    __shared__ float As[16][68];
    __shared__ float Bs[16][68];
    int tid = threadIdx.x;
    int tx = tid & 15, ty = tid >> 4;
    int bm = blockIdx.x * 64;
    int y = blockIdx.y;
    const float* A;
    const float* W;
    if (y == 0)      { A = h1; W = fcW1; }
    else if (y <= 2) { A = z0; W = shW0 + (size_t)(y - 1) * 64 * K; }
    else             { A = z0; W = scW0 + (size_t)(y - 3) * 64 * K; }
    int m = tid >> 2;
    int kk0 = (tid & 3) * 4;
    int arow = bm + m;
    bool avalid = arow < M;
    const float* Ap = A + (size_t)arow * K + kk0;
    const float* Wp = W + (size_t)m * K + kk0;

    float4 av = make_float4(0.f, 0.f, 0.f, 0.f);
    if (avalid) av = *(const float4*)(Ap);
    float4 bv = *(const float4*)(Wp);

    float acc[4][4] = {};
    constexpr int T = K >> 4;
    for (int t = 0; t < T; ++t) {
        As[kk0 + 0][m] = av.x; As[kk0 + 1][m] = av.y;
        As[kk0 + 2][m] = av.z; As[kk0 + 3][m] = av.w;
        Bs[kk0 + 0][m] = bv.x; Bs[kk0 + 1][m] = bv.y;
        Bs[kk0 + 2][m] = bv.z; Bs[kk0 + 3][m] = bv.w;
        __syncthreads();
        if (t + 1 < T) {
            int ko = (t + 1) << 4;
            if (avalid) av = *(const float4*)(Ap + ko);
            bv = *(const float4*)(Wp + ko);
        }
#pragma unroll
        for (int kk = 0; kk < 16; ++kk) {
            float a[4], b[4];
            *(float4*)a = *(const float4*)(&As[kk][ty * 4]);
            *(float4*)b = *(const float4*)(&Bs[kk][tx * 4]);
#pragma unroll
            for (int i = 0; i < 4; ++i)
#pragma unroll
                for (int j = 0; j < 4; ++j) acc[i][j] += a[i] * b[j];
        }
        __syncthreads();
    }
    int r0 = bm + ty * 4;
    int lc = tx * 4;
    if (y == 0)      gemm_epilogue4<1, false>(acc, fcb1, z1, 64, 0, r0, lc, M);
    else if (y <= 2) gemm_epilogue4<2, true>(acc, shb0, k0, 128, (y - 1) * 64, r0, lc, M);
    else             gemm_epilogue4<3, true>(acc, scb0, l0, 128, (y - 3) * 64, r0, lc, M);
}

// per-head weight select: compile-time for CPER=64 (h==j), cndmask on lane bit 5 for CPER=32
template <int CPER>
__device__ __forceinline__ float pick_w(float4 w, int j, int lane) {
    if constexpr (CPER == 64) {
        return j == 0 ? w.x : (j == 1 ? w.y : (j == 2 ? w.z : w.w));
    } else {
        float lo = (j == 0) ? w.x : w.z;
        float hi = (j == 0) ? w.y : w.w;
        return (lane & 32) ? hi : lo;
    }
}

// ---------------- GAT aggregation: one wave per node, inline native-exp edge weights ----
template <int F, int CPER>
__global__ __launch_bounds__(256) void agg_kernel(const float* __restrict__ xw,
                                                  const int* __restrict__ rowptr,
                                                  const int* __restrict__ csr,
                                                  const float* __restrict__ s,
                                                  const float* __restrict__ d,
                                                  const float* __restrict__ bias,
                                                  float* __restrict__ out) {
    int wave = threadIdx.x >> 6;
    int lane = threadIdx.x & 63;
    int n = blockIdx.x * 4 + wave;
    if (n >= N_NODES) return;
    constexpr int J = F / 64;

    float4 d4 = *(const float4*)(d + 4 * (size_t)n);
    float4 s4 = *(const float4*)(s + 4 * (size_t)n);
    float4 wl = edge_w(s4, d4);  // self-loop weight
    float den[NHEADS] = {wl.x, wl.y, wl.z, wl.w};
    float acc[J];
#pragma unroll
    for (int j = 0; j < J; ++j) {
        int c = j * 64 + lane;
        acc[j] = pick_w<CPER>(wl, j, lane) * xw[(size_t)n * F + c];
    }

    int beg = rowptr[n], end = rowptr[n + 1];
    int idx = beg;
    for (; idx + 2 <= end; idx += 2) {
        int sa = csr[idx], sb = csr[idx + 1];
        float4 wa = edge_w(*(const float4*)(s + 4 * (size_t)sa), d4);
        float4 wb = edge_w(*(const float4*)(s + 4 * (size_t)sb), d4);
        den[0] += wa.x + wb.x;
        den[1] += wa.y + wb.y;
        den[2] += wa.z + wb.z;
        den[3] += wa.w + wb.w;
        const float* ra = xw + (size_t)sa * F;
        const float* rb = xw + (size_t)sb * F;
#pragma unroll
        for (int j = 0; j < J; ++j) {
            int c = j * 64 + lane;
            acc[j] += pick_w<CPER>(wa, j, lane) * ra[c];
            acc[j] += pick_w<CPER>(wb, j, lane) * rb[c];
        }
    }
    if (idx < end) {
        int sa = csr[idx];
        float4 wa = edge_w(*(const float4*)(s + 4 * (size_t)sa), d4);
        den[0] += wa.x;
        den[1] += wa.y;
        den[2] += wa.z;
        den[3] += wa.w;
        const float* ra = xw + (size_t)sa * F;
#pragma unroll
        for (int j = 0; j < J; ++j) {
            int c = j * 64 + lane;
            acc[j] += pick_w<CPER>(wa, j, lane) * ra[c];
        }
    }

#pragma unroll
    for (int j = 0; j < J; ++j) {
        int c = j * 64 + lane;
        float dv;
        if constexpr (CPER == 64) dv = den[j];
        else dv = (lane & 32) ? den[2 * j + 1] : den[2 * j];
        out[(size_t)n * F + c] = acc[j] / (dv + 1e-16f) + bias[c];
    }
}

// ---------------- Weibull reparameterization: native v_log/v_exp power chain ----------------
// v = -ln(1-u) = ln2 * t with t = -log2(1-u)
// v^invk = exp2(invk*log2(v)) = exp2(invk*log2(t) + invk*log2(ln2))
// t=0 -> log2(t)=-inf -> exp2(-inf)=0, matching pow(0, invk)=0.
__device__ __forceinline__ void theta_work(const float* __restrict__ eps,
                                           const float* __restrict__ kptr,
                                           float* __restrict__ lptr,
                                           float* __restrict__ theta, int i, int ZN) {
    float k = kptr[i];
    float invk = __builtin_amdgcn_rcpf(k);          // k in [0.1,1000], ~1ulp
    float lg = lgammaf(1.0f + invk);                // keep libm: 1 call, accuracy-critical
    float l = lptr[i] * __builtin_amdgcn_exp2f(-lg * LOG2E);  // l / Gamma(1+invk)
    lptr[i] = l;
    float c = invk * LOG2_LN2;
    float acc = 0.0f;
#pragma unroll
    for (int ss = 0; ss < 10; ++ss) {
        float u = eps[(size_t)ss * ZN + i];
        float t = -__builtin_amdgcn_logf(fmaxf(1.0f - u, RMIN));   // -log2(1-u) >= 0
        acc += __builtin_amdgcn_exp2f(invk * __builtin_amdgcn_logf(t) + c);
    }
    float th = l * acc * 0.1f;
    th = fminf(fmaxf(th, RMIN), THETA_MAX);
    theta[i] = th;
}

__global__ __launch_bounds__(256) void theta2_kernel(const float* __restrict__ eps0,
                                                     float* __restrict__ k0,
                                                     float* __restrict__ l0,
                                                     float* __restrict__ th0,
                                                     const float* __restrict__ eps1,
                                                     float* __restrict__ k1,
                                                     float* __restrict__ l1,
                                                     float* __restrict__ th1) {
    int i = blockIdx.x * 256 + threadIdx.x;
    if (i < 2560000) {
        theta_work(eps0, k0, l0, th0, i, 2560000);
    } else {
        int j = i - 2560000;
        if (j < 1280000) theta_work(eps1, k1, l1, th1, j, 1280000);
    }
}

extern "C" void kernel_launch(void* const* d_in, const int* in_sizes, int n_in,
                              void* d_out, int out_size, void* d_ws, size_t ws_size,
                              hipStream_t stream) {
    const float* x     = (const float*)d_in[0];
    const int*   eidx  = (const int*)d_in[1];
    const float* gatW0 = (const float*)d_in[2];
    const float* asrc0 = (const float*)d_in[3];
    const float* adst0 = (const float*)d_in[4];
    const float* gatb0 = (const float*)d_in[5];
    const float* fcW0  = (const float*)d_in[6];
    const float* fcb0  = (const float*)d_in[7];
    const float* shW0  = (const float*)d_in[8];
    const float* shb0  = (const float*)d_in[9];
    const float* scW0  = (const float*)d_in[10];
    const float* scb0  = (const float*)d_in[11];
    const float* gatW1 = (const float*)d_in[12];
    const float* asrc1 = (const float*)d_in[13];
    const float* adst1 = (const float*)d_in[14];
    const float* gatb1 = (const float*)d_in[15];
    const float* fcW1  = (const float*)d_in[16];
    const float* fcb1  = (const float*)d_in[17];
    const float* shW1  = (const float*)d_in[18];
    const float* shb1  = (const float*)d_in[19];
    const float* scW1  = (const float*)d_in[20];
    const float* scb1  = (const float*)d_in[21];
    const float* eps0  = (const float*)d_in[22];
    const float* eps1  = (const float*)d_in[23];

    const int* e_src = eidx;
    const int* e_dst = eidx + E_EDGES;

    // workspace carve-up
    size_t off = 0;
    auto carve = [&](size_t elems) {
        void* p = (char*)d_ws + off;
        off += ((elems * 4 + 255) / 256) * 256;
        return p;
    };
    float* xw0 = (float*)carve(20000u * 256);
    float* h0  = (float*)carve(20000u * 256);
    float* z0  = (float*)carve(20000u * 128);
    float* xw1 = (float*)carve(20000u * 128);
    float* h1  = (float*)carve(20000u * 128);
    float* z1  = (float*)carve(20000u * 64);
    float* s0  = (float*)carve(20000u * 4);
    float* d0  = (float*)carve(20000u * 4);
    float* s1  = (float*)carve(20000u * 4);
    float* d1  = (float*)carve(20000u * 4);
    int* deg    = (int*)carve(20000);
    int* rowptr = (int*)carve(20001);
    int* cursor = (int*)carve(20000);
    int* csr    = (int*)carve(E_EDGES);

    float* out    = (float*)d_out;
    float* theta0 = out;
    float* theta1 = out + 2560000;
    float* k0     = out + 3840000;
    float* k1     = out + 6400000;
    float* l0     = out + 7680000;
    float* l1     = out + 10240000;

    const int M = N_NODES;
    dim3 blk(256);
    const int GX = (N_NODES + 63) / 64;  // 313

    // CSR build
    (void)hipMemsetAsync(deg, 0, N_NODES * sizeof(int), stream);
    count_kernel<<<(E_EDGES + 255) / 256, blk, 0, stream>>>(e_dst, deg);
    scan_kernel<<<1, blk, 0, stream>>>(deg, rowptr, cursor);
    scatter_kernel<<<(E_EDGES + 255) / 256, blk, 0, stream>>>(e_src, e_dst, cursor, csr);

    // layer 0: xw0 = x @ gatW0^T, fused s0/d0
    gemm64_kernel<0, 0, false, 1, 64><<<dim3(GX, 4), blk, 0, stream>>>(
        x, gatW0, nullptr, nullptr, nullptr, xw0, nullptr,
        asrc0, adst0, s0, d0, M, 256, 256, 0);
    agg_kernel<256, 64><<<5000, blk, 0, stream>>>(xw0, rowptr, csr, s0, d0, gatb0, h0);

    // merged: z0 = softplus(h0 @ fcW0^T + b) | xw1 = h0 @ gatW1^T, fused s1/d1 on xw1 cols
    gemm64_kernel<1, 0, false, 2, 32><<<dim3(GX, 4), blk, 0, stream>>>(
        h0, fcW0, gatW1, fcb0, nullptr, z0, xw1,
        asrc1, adst1, s1, d1, M, 256, 128, 128);
    agg_kernel<128, 32><<<5000, blk, 0, stream>>>(xw1, rowptr, csr, s1, d1, gatb1, h1);

    // merged tail: z1 gemm + z0-heads gemms (K=128 for all five y-tiles)
    gemmC_kernel<<<dim3(GX, 5), blk, 0, stream>>>(
        h1, fcW1, fcb1, z1, z0, shW0, shb0, k0, scW0, scb0, l0, M);

    // z1 heads (K=64): k1 = clip(sp(.)), l1 = max(sp(.), RMIN), transposed
    gemm64_kernel<2, 3, true, 0, 64><<<dim3(GX, 2), blk, 0, stream>>>(
        z1, shW1, scW1, shb1, scb1, k1, l1,
        nullptr, nullptr, nullptr, nullptr, M, 64, 64, 64);

    // reparameterize both levels (finalizes l in-place, writes theta)
    theta2_kernel<<<15000, blk, 0, stream>>>(eps0, k0, l0, theta0, eps1, k1, l1, theta1);
}

// Round 6
// 562.723 us; speedup vs baseline: 1.2155x; 1.0431x over previous
//
#include <hip/hip_runtime.h>
#include <math.h>

#define N_NODES 20000
#define E_EDGES 320000
#define NHEADS 4
#define RMIN 2.2e-10f
#define THETA_MAX 1000.0f
#define SLOPE 0.2f
#define LOG2E 1.4426950408889634f
#define LOG2_LN2 -0.5287663729448977f  /* log2(ln 2) */

__device__ __forceinline__ float softplus_f(float x) {
    // log(1+exp(x)), stable; matches jax.nn.softplus (libm path: feeds outputs k,l,z)
    return fmaxf(x, 0.0f) + log1pf(expf(-fabsf(x)));
}

// exp(leaky_relu(s+d)) for one head — native v_exp_f32
__device__ __forceinline__ float ew1(float sv, float dh) {
    float e = (sv + dh) * LOG2E;
    e = e > 0.f ? e : SLOPE * e;
    return __builtin_amdgcn_exp2f(e);
}

// ---------------- CSR build ----------------
__global__ __launch_bounds__(256) void count_kernel(const int* __restrict__ dst,
                                                    int* __restrict__ deg) {
    int e = blockIdx.x * 256 + threadIdx.x;
    if (e < E_EDGES) atomicAdd(&deg[dst[e]], 1);
}

__global__ __launch_bounds__(256) void scan_kernel(const int* __restrict__ deg,
                                                   int* __restrict__ rowptr,
                                                   int* __restrict__ cursor) {
    __shared__ int part[256];
    int t = threadIdx.x;
    const int CH = (N_NODES + 255) / 256;  // 79
    int base = t * CH;
    int sum = 0;
    for (int i = 0; i < CH; ++i) {
        int idx = base + i;
        if (idx < N_NODES) sum += deg[idx];
    }
    part[t] = sum;
    __syncthreads();
    // Hillis-Steele inclusive scan
    for (int off = 1; off < 256; off <<= 1) {
        int v = (t >= off) ? part[t - off] : 0;
        __syncthreads();
        part[t] += v;
        __syncthreads();
    }
    int run = (t == 0) ? 0 : part[t - 1];
    for (int i = 0; i < CH; ++i) {
        int idx = base + i;
        if (idx < N_NODES) {
            rowptr[idx] = run;
            cursor[idx] = run;
            run += deg[idx];
        }
    }
    if (t == 255) rowptr[N_NODES] = run;
}

__global__ __launch_bounds__(256) void scatter_kernel(const int* __restrict__ src,
                                                      const int* __restrict__ dst,
                                                      int* __restrict__ cursor,
                                                      int* __restrict__ csr) {
    int e = blockIdx.x * 256 + threadIdx.x;
    if (e < E_EDGES) {
        int p = atomicAdd(&cursor[dst[e]], 1);
        csr[p] = src[e];
    }
}

// ---------------- GEMM: 64x64 tile, 4x4 micro-tile, reg-prefetch ----------------
// out = A[M,K] * [W0;W1][NO,K]^T. Columns [0,split) -> out0 (MODE0), [split,NO) -> out1 (MODE1).
// MODE: 0 raw, 1 softplus(v+b), 2 clip(softplus(v+b),0.1,1000), 3 max(softplus(v+b),RMIN)
// TRANS: write out[col*M + row]. SDW: 0 none, 1 fused s/d on out0 cols, 2 on out1 cols.
template <int MODE, bool TRANS>
__device__ __forceinline__ void gemm_epilogue4(const float acc[4][4],
                                               const float* __restrict__ bp,
                                               float* __restrict__ op,
                                               int ow, int colbase, int r0, int lc, int M) {
    float bv[4] = {0.f, 0.f, 0.f, 0.f};
    if (MODE != 0) *(float4*)bv = *(const float4*)(bp + colbase + lc);
    float vals[4][4];
#pragma unroll
    for (int i = 0; i < 4; ++i)
#pragma unroll
        for (int j = 0; j < 4; ++j) {
            float v = acc[i][j];
            if (MODE == 1) v = softplus_f(v + bv[j]);
            else if (MODE == 2) { v = softplus_f(v + bv[j]); v = fminf(fmaxf(v, 0.1f), 1000.0f); }
            else if (MODE == 3) { v = fmaxf(softplus_f(v + bv[j]), RMIN); }
            vals[i][j] = v;
        }
    if (!TRANS) {
#pragma unroll
        for (int i = 0; i < 4; ++i) {
            int row = r0 + i;
            if (row < M) *(float4*)(op + (size_t)row * ow + colbase + lc) = *(float4*)vals[i];
        }
    } else {
        if (r0 + 3 < M) {
#pragma unroll
            for (int j = 0; j < 4; ++j) {
                int c = colbase + lc + j;
                float col[4] = {vals[0][j], vals[1][j], vals[2][j], vals[3][j]};
                *(float4*)(op + (size_t)c * M + r0) = *(float4*)col;
            }
        } else {
#pragma unroll
            for (int i = 0; i < 4; ++i) {
                int row = r0 + i;
                if (row < M)
#pragma unroll
                    for (int j = 0; j < 4; ++j) op[(size_t)(colbase + lc + j) * M + row] = vals[i][j];
            }
        }
    }
}

template <int MODE0, int MODE1, bool TRANS, int SDW, int CPER>
__global__ __launch_bounds__(256) void gemm64_kernel(const float* __restrict__ A,
                                                     const float* __restrict__ W0,
                                                     const float* __restrict__ W1,
                                                     const float* __restrict__ b0p,
                                                     const float* __restrict__ b1p,
                                                     float* __restrict__ out0,
                                                     float* __restrict__ out1,
                                                     const float* __restrict__ asrc,
                                                     const float* __restrict__ adst,
                                                     float* __restrict__ sp,
                                                     float* __restrict__ dp,
                                                     int M, int K, int split, int no1) {
    __shared__ float As[16][68];
    __shared__ float Bs[16][68];
    int tid = threadIdx.x;
    int tx = tid & 15, ty = tid >> 4;
    int bm = blockIdx.x * 64;
    int bn = blockIdx.y * 64;
    bool first = bn < split;
    const float* W = first ? (W0 + (size_t)bn * K) : (W1 + (size_t)(bn - split) * K);
    int m = tid >> 2;            // 0..63
    int kk0 = (tid & 3) * 4;     // 0,4,8,12
    int arow = bm + m;
    bool avalid = arow < M;
    const float* Ap = A + (size_t)arow * K + kk0;
    const float* Wp = W + (size_t)m * K + kk0;

    float4 av = make_float4(0.f, 0.f, 0.f, 0.f);
    if (avalid) av = *(const float4*)(Ap);
    float4 bv = *(const float4*)(Wp);

    float acc[4][4] = {};
    int T = K >> 4;
    for (int t = 0; t < T; ++t) {
        As[kk0 + 0][m] = av.x; As[kk0 + 1][m] = av.y;
        As[kk0 + 2][m] = av.z; As[kk0 + 3][m] = av.w;
        Bs[kk0 + 0][m] = bv.x; Bs[kk0 + 1][m] = bv.y;
        Bs[kk0 + 2][m] = bv.z; Bs[kk0 + 3][m] = bv.w;
        __syncthreads();
        if (t + 1 < T) {
            int ko = (t + 1) << 4;
            if (avalid) av = *(const float4*)(Ap + ko);
            bv = *(const float4*)(Wp + ko);
        }
#pragma unroll
        for (int kk = 0; kk < 16; ++kk) {
            float a[4], b[4];
            *(float4*)a = *(const float4*)(&As[kk][ty * 4]);
            *(float4*)b = *(const float4*)(&Bs[kk][tx * 4]);
#pragma unroll
            for (int i = 0; i < 4; ++i)
#pragma unroll
                for (int j = 0; j < 4; ++j) acc[i][j] += a[i] * b[j];
        }
        __syncthreads();
    }
    int r0 = bm + ty * 4;
    int lc = tx * 4;

    // fused attention-logit reduction on RAW acc (the sd cols are always MODE 0 / raw)
    if constexpr (SDW != 0) {
        bool dosd = (SDW == 1) ? first : !first;
        if (dosd) {
            int bo = (SDW == 1) ? bn : bn - split;  // column offset within the xw feature dim
            float4 as4 = *(const float4*)(asrc + bo + lc);
            float4 ad4 = *(const float4*)(adst + bo + lc);
            float ps[4], pd[4];
#pragma unroll
            for (int i = 0; i < 4; ++i) {
                ps[i] = acc[i][0] * as4.x + acc[i][1] * as4.y + acc[i][2] * as4.z + acc[i][3] * as4.w;
                pd[i] = acc[i][0] * ad4.x + acc[i][1] * ad4.y + acc[i][2] * ad4.z + acc[i][3] * ad4.w;
            }
#pragma unroll
            for (int off = (CPER == 64 ? 8 : 4); off >= 1; off >>= 1) {
#pragma unroll
                for (int i = 0; i < 4; ++i) {
                    ps[i] += __shfl_xor(ps[i], off, 64);
                    pd[i] += __shfl_xor(pd[i], off, 64);
                }
            }
            bool lanesel;
            int h;
            if constexpr (CPER == 64) { lanesel = (tx == 0); h = bo >> 6; }
            else { lanesel = ((tx & 7) == 0); h = (bo >> 5) + (tx >> 3); }
            if (lanesel) {
#pragma unroll
                for (int i = 0; i < 4; ++i) {
                    int row = r0 + i;
                    if (row < M) {
                        sp[row * NHEADS + h] = ps[i];
                        dp[row * NHEADS + h] = pd[i];
                    }
                }
            }
        }
    }

    if (first) gemm_epilogue4<MODE0, TRANS>(acc, b0p, out0, split, bn, r0, lc, M);
    else       gemm_epilogue4<MODE1, TRANS>(acc, b1p, out1, no1, bn - split, r0, lc, M);
}

// ---------------- merged tail GEMM: y=0 -> z1 = sp(h1@fcW1^T+b); y=1..4 -> k0/l0 heads ----
__global__ __launch_bounds__(256) void gemmC_kernel(const float* __restrict__ h1,
                                                    const float* __restrict__ fcW1,
                                                    const float* __restrict__ fcb1,
                                                    float* __restrict__ z1,
                                                    const float* __restrict__ z0,
                                                    const float* __restrict__ shW0,
                                                    const float* __restrict__ shb0,
                                                    float* __restrict__ k0,
                                                    const float* __restrict__ scW0,
                                                    const float* __restrict__ scb0,
                                                    float* __restrict__ l0,
                                                    int M) {
    constexpr int K = 128;
    __shared__ float As[16][68];
    __shared__ float Bs[16][68];
    int tid = threadIdx.x;
    int tx = tid & 15, ty = tid >> 4;
    int bm = blockIdx.x * 64;
    int y = blockIdx.y;
    const float* A;
    const float* W;
    if (y == 0)      { A = h1; W = fcW1; }
    else if (y <= 2) { A = z0; W = shW0 + (size_t)(y - 1) * 64 * K; }
    else             { A = z0; W = scW0 + (size_t)(y - 3) * 64 * K; }
    int m = tid >> 2;
    int kk0 = (tid & 3) * 4;
    int arow = bm + m;
    bool avalid = arow < M;
    const float* Ap = A + (size_t)arow * K + kk0;
    const float* Wp = W + (size_t)m * K + kk0;

    float4 av = make_float4(0.f, 0.f, 0.f, 0.f);
    if (avalid) av = *(const float4*)(Ap);
    float4 bv = *(const float4*)(Wp);

    float acc[4][4] = {};
    constexpr int T = K >> 4;
    for (int t = 0; t < T; ++t) {
        As[kk0 + 0][m] = av.x; As[kk0 + 1][m] = av.y;
        As[kk0 + 2][m] = av.z; As[kk0 + 3][m] = av.w;
        Bs[kk0 + 0][m] = bv.x; Bs[kk0 + 1][m] = bv.y;
        Bs[kk0 + 2][m] = bv.z; Bs[kk0 + 3][m] = bv.w;
        __syncthreads();
        if (t + 1 < T) {
            int ko = (t + 1) << 4;
            if (avalid) av = *(const float4*)(Ap + ko);
            bv = *(const float4*)(Wp + ko);
        }
#pragma unroll
        for (int kk = 0; kk < 16; ++kk) {
            float a[4], b[4];
            *(float4*)a = *(const float4*)(&As[kk][ty * 4]);
            *(float4*)b = *(const float4*)(&Bs[kk][tx * 4]);
#pragma unroll
            for (int i = 0; i < 4; ++i)
#pragma unroll
                for (int j = 0; j < 4; ++j) acc[i][j] += a[i] * b[j];
        }
        __syncthreads();
    }
    int r0 = bm + ty * 4;
    int lc = tx * 4;
    if (y == 0)      gemm_epilogue4<1, false>(acc, fcb1, z1, 64, 0, r0, lc, M);
    else if (y <= 2) gemm_epilogue4<2, true>(acc, shb0, k0, 128, (y - 1) * 64, r0, lc, M);
    else             gemm_epilogue4<3, true>(acc, scb0, l0, 128, (y - 3) * 64, r0, lc, M);
}

// ---------------- GAT aggregation: one wave per node, per-lane VEC-column blocking ----
// Lane owns VEC=F/64 consecutive columns (c0=lane*VEC); all VEC columns fall in ONE head
// h=lane>>4 (F=256: c0/64, F=128: c0/32 — both = lane>>4). Per edge: 1 gathered s-dword,
// 1 exp, 1 vector row load, VEC FMAs. den/acc summation order per (n,c) matches the
// previous per-edge-sequential order exactly.
template <int F>
__global__ __launch_bounds__(256) void agg_kernel(const float* __restrict__ xw,
                                                  const int* __restrict__ rowptr,
                                                  const int* __restrict__ csr,
                                                  const float* __restrict__ s,
                                                  const float* __restrict__ d,
                                                  const float* __restrict__ bias,
                                                  float* __restrict__ out) {
    constexpr int VEC = F / 64;
    int wave = threadIdx.x >> 6;
    int lane = threadIdx.x & 63;
    int n = blockIdx.x * 4 + wave;
    if (n >= N_NODES) return;
    int c0 = lane * VEC;
    int h = lane >> 4;

    float dh = d[(size_t)n * NHEADS + h];
    float w = ew1(s[(size_t)n * NHEADS + h], dh);  // self-loop weight (own head)
    float den = w;
    float acc[VEC];
    {
        float r[VEC];
        const float* rp = xw + (size_t)n * F + c0;
        if constexpr (VEC == 4) *(float4*)r = *(const float4*)rp;
        else                    *(float2*)r = *(const float2*)rp;
#pragma unroll
        for (int v = 0; v < VEC; ++v) acc[v] = w * r[v];
    }

    int idx = rowptr[n], end = rowptr[n + 1];
    for (; idx + 4 <= end; idx += 4) {
        int n0 = csr[idx], n1 = csr[idx + 1], n2 = csr[idx + 2], n3 = csr[idx + 3];
        float w0 = ew1(s[(size_t)n0 * NHEADS + h], dh);
        float w1 = ew1(s[(size_t)n1 * NHEADS + h], dh);
        float w2 = ew1(s[(size_t)n2 * NHEADS + h], dh);
        float w3 = ew1(s[(size_t)n3 * NHEADS + h], dh);
        den += w0; den += w1; den += w2; den += w3;
        float r0[VEC], r1[VEC], r2[VEC], r3[VEC];
        const float* p0 = xw + (size_t)n0 * F + c0;
        const float* p1 = xw + (size_t)n1 * F + c0;
        const float* p2 = xw + (size_t)n2 * F + c0;
        const float* p3 = xw + (size_t)n3 * F + c0;
        if constexpr (VEC == 4) {
            *(float4*)r0 = *(const float4*)p0; *(float4*)r1 = *(const float4*)p1;
            *(float4*)r2 = *(const float4*)p2; *(float4*)r3 = *(const float4*)p3;
        } else {
            *(float2*)r0 = *(const float2*)p0; *(float2*)r1 = *(const float2*)p1;
            *(float2*)r2 = *(const float2*)p2; *(float2*)r3 = *(const float2*)p3;
        }
#pragma unroll
        for (int v = 0; v < VEC; ++v) {
            acc[v] += w0 * r0[v];
            acc[v] += w1 * r1[v];
            acc[v] += w2 * r2[v];
            acc[v] += w3 * r3[v];
        }
    }
    for (; idx < end; ++idx) {
        int n0 = csr[idx];
        float w0 = ew1(s[(size_t)n0 * NHEADS + h], dh);
        den += w0;
        float r0[VEC];
        const float* p0 = xw + (size_t)n0 * F + c0;
        if constexpr (VEC == 4) *(float4*)r0 = *(const float4*)p0;
        else                    *(float2*)r0 = *(const float2*)p0;
#pragma unroll
        for (int v = 0; v < VEC; ++v) acc[v] += w0 * r0[v];
    }

    float rden = 1.0f / (den + 1e-16f);
    float o[VEC], bvv[VEC];
    const float* bp = bias + c0;
    if constexpr (VEC == 4) *(float4*)bvv = *(const float4*)bp;
    else                    *(float2*)bvv = *(const float2*)bp;
#pragma unroll
    for (int v = 0; v < VEC; ++v) o[v] = acc[v] * rden + bvv[v];
    float* op = out + (size_t)n * F + c0;
    if constexpr (VEC == 4) *(float4*)op = *(float4*)o;
    else                    *(float2*)op = *(float2*)o;
}

// ---------------- Weibull reparameterization: native v_log/v_exp power chain ----------------
__device__ __forceinline__ void theta_work(const float* __restrict__ eps,
                                           const float* __restrict__ kptr,
                                           float* __restrict__ lptr,
                                           float* __restrict__ theta, int i, int ZN) {
    float k = kptr[i];
    float invk = __builtin_amdgcn_rcpf(k);          // k in [0.1,1000], ~1ulp
    float lg = lgammaf(1.0f + invk);                // keep libm: 1 call, accuracy-critical
    float l = lptr[i] * __builtin_amdgcn_exp2f(-lg * LOG2E);  // l / Gamma(1+invk)
    lptr[i] = l;
    float c = invk * LOG2_LN2;
    float acc = 0.0f;
#pragma unroll
    for (int ss = 0; ss < 10; ++ss) {
        float u = eps[(size_t)ss * ZN + i];
        float t = -__builtin_amdgcn_logf(fmaxf(1.0f - u, RMIN));   // -log2(1-u) >= 0
        acc += __builtin_amdgcn_exp2f(invk * __builtin_amdgcn_logf(t) + c);
    }
    float th = l * acc * 0.1f;
    th = fminf(fmaxf(th, RMIN), THETA_MAX);
    theta[i] = th;
}

__global__ __launch_bounds__(256) void theta2_kernel(const float* __restrict__ eps0,
                                                     float* __restrict__ k0,
                                                     float* __restrict__ l0,
                                                     float* __restrict__ th0,
                                                     const float* __restrict__ eps1,
                                                     float* __restrict__ k1,
                                                     float* __restrict__ l1,
                                                     float* __restrict__ th1) {
    int i = blockIdx.x * 256 + threadIdx.x;
    if (i < 2560000) {
        theta_work(eps0, k0, l0, th0, i, 2560000);
    } else {
        int j = i - 2560000;
        if (j < 1280000) theta_work(eps1, k1, l1, th1, j, 1280000);
    }
}

extern "C" void kernel_launch(void* const* d_in, const int* in_sizes, int n_in,
                              void* d_out, int out_size, void* d_ws, size_t ws_size,
                              hipStream_t stream) {
    const float* x     = (const float*)d_in[0];
    const int*   eidx  = (const int*)d_in[1];
    const float* gatW0 = (const float*)d_in[2];
    const float* asrc0 = (const float*)d_in[3];
    const float* adst0 = (const float*)d_in[4];
    const float* gatb0 = (const float*)d_in[5];
    const float* fcW0  = (const float*)d_in[6];
    const float* fcb0  = (const float*)d_in[7];
    const float* shW0  = (const float*)d_in[8];
    const float* shb0  = (const float*)d_in[9];
    const float* scW0  = (const float*)d_in[10];
    const float* scb0  = (const float*)d_in[11];
    const float* gatW1 = (const float*)d_in[12];
    const float* asrc1 = (const float*)d_in[13];
    const float* adst1 = (const float*)d_in[14];
    const float* gatb1 = (const float*)d_in[15];
    const float* fcW1  = (const float*)d_in[16];
    const float* fcb1  = (const float*)d_in[17];
    const float* shW1  = (const float*)d_in[18];
    const float* shb1  = (const float*)d_in[19];
    const float* scW1  = (const float*)d_in[20];
    const float* scb1  = (const float*)d_in[21];
    const float* eps0  = (const float*)d_in[22];
    const float* eps1  = (const float*)d_in[23];

    const int* e_src = eidx;
    const int* e_dst = eidx + E_EDGES;

    // workspace carve-up
    size_t off = 0;
    auto carve = [&](size_t elems) {
        void* p = (char*)d_ws + off;
        off += ((elems * 4 + 255) / 256) * 256;
        return p;
    };
    float* xw0 = (float*)carve(20000u * 256);
    float* h0  = (float*)carve(20000u * 256);
    float* z0  = (float*)carve(20000u * 128);
    float* xw1 = (float*)carve(20000u * 128);
    float* h1  = (float*)carve(20000u * 128);
    float* z1  = (float*)carve(20000u * 64);
    float* s0  = (float*)carve(20000u * 4);
    float* d0  = (float*)carve(20000u * 4);
    float* s1  = (float*)carve(20000u * 4);
    float* d1  = (float*)carve(20000u * 4);
    int* deg    = (int*)carve(20000);
    int* rowptr = (int*)carve(20001);
    int* cursor = (int*)carve(20000);
    int* csr    = (int*)carve(E_EDGES);

    float* out    = (float*)d_out;
    float* theta0 = out;
    float* theta1 = out + 2560000;
    float* k0     = out + 3840000;
    float* k1     = out + 6400000;
    float* l0     = out + 7680000;
    float* l1     = out + 10240000;

    const int M = N_NODES;
    dim3 blk(256);
    const int GX = (N_NODES + 63) / 64;  // 313

    // CSR build
    (void)hipMemsetAsync(deg, 0, N_NODES * sizeof(int), stream);
    count_kernel<<<(E_EDGES + 255) / 256, blk, 0, stream>>>(e_dst, deg);
    scan_kernel<<<1, blk, 0, stream>>>(deg, rowptr, cursor);
    scatter_kernel<<<(E_EDGES + 255) / 256, blk, 0, stream>>>(e_src, e_dst, cursor, csr);

    // layer 0: xw0 = x @ gatW0^T, fused s0/d0
    gemm64_kernel<0, 0, false, 1, 64><<<dim3(GX, 4), blk, 0, stream>>>(
        x, gatW0, nullptr, nullptr, nullptr, xw0, nullptr,
        asrc0, adst0, s0, d0, M, 256, 256, 0);
    agg_kernel<256><<<5000, blk, 0, stream>>>(xw0, rowptr, csr, s0, d0, gatb0, h0);

    // merged: z0 = softplus(h0 @ fcW0^T + b) | xw1 = h0 @ gatW1^T, fused s1/d1 on xw1 cols
    gemm64_kernel<1, 0, false, 2, 32><<<dim3(GX, 4), blk, 0, stream>>>(
        h0, fcW0, gatW1, fcb0, nullptr, z0, xw1,
        asrc1, adst1, s1, d1, M, 256, 128, 128);
    agg_kernel<128><<<5000, blk, 0, stream>>>(xw1, rowptr, csr, s1, d1, gatb1, h1);

    // merged tail: z1 gemm + z0-heads gemms (K=128 for all five y-tiles)
    gemmC_kernel<<<dim3(GX, 5), blk, 0, stream>>>(
        h1, fcW1, fcb1, z1, z0, shW0, shb0, k0, scW0, scb0, l0, M);

    // z1 heads (K=64): k1 = clip(sp(.)), l1 = max(sp(.), RMIN), transposed
    gemm64_kernel<2, 3, true, 0, 64><<<dim3(GX, 2), blk, 0, stream>>>(
        z1, shW1, scW1, shb1, scb1, k1, l1,
        nullptr, nullptr, nullptr, nullptr, M, 64, 64, 64);

    // reparameterize both levels (finalizes l in-place, writes theta)
    theta2_kernel<<<15000, blk, 0, stream>>>(eps0, k0, l0, theta0, eps1, k1, l1, theta1);
}